// Round 9
// baseline (3436.436 us; speedup 1.0000x reference)
//
#include <hip/hip_runtime.h>

#define DEV __device__ __forceinline__

constexpr int NB  = 32;
constexpr int LXc = 256;
constexpr int LYc = 128;
constexpr int Dc  = 768;
constexpr int NH  = 12;
constexpr int FFc = 3072;

typedef unsigned short u16;
typedef float f32x4 __attribute__((ext_vector_type(4)));
typedef short s16x8 __attribute__((ext_vector_type(8)));

DEV u16 f2bf(float f) {
  unsigned u = __float_as_uint(f);
  u += 0x7FFFu + ((u >> 16) & 1u);
  return (u16)(u >> 16);
}
DEV float bf2f(u16 w) { return __uint_as_float(((unsigned)w) << 16); }
DEV float ldf(const void* p, long long i, int isbf) {
  return isbf ? bf2f(((const u16*)p)[i]) : ((const float*)p)[i];
}

DEV void gload16(const void* g, void* l) {
  __builtin_amdgcn_global_load_lds(
      (const __attribute__((address_space(1))) void*)g,
      (__attribute__((address_space(3))) void*)l, 16, 0, 0);
}
DEV void barx() {
  asm volatile("" ::: "memory");
  __builtin_amdgcn_s_barrier();
  asm volatile("" ::: "memory");
}

// ---------------- dtype detection ----------------
__global__ void k_detect(const u16* y, int* flag) {
  if (threadIdx.x == 0) {
    int cnt = 0;
    for (int i = 0; i < 256; ++i) {
      u16 w = y[i];
      int e = (w >> 7) & 0xFF;
      if (e == 0 || (e >= 112 && e <= 140)) cnt++;
    }
    *flag = (cnt >= 200) ? 1 : 0;
  }
}

// raw -> bf16 stream
__global__ void k_ingest_b(const void* src, u16* dst, long long n, const int* flag) {
  int isbf = *flag;
  long long i = (long long)blockIdx.x * blockDim.x + threadIdx.x;
  long long st = (long long)gridDim.x * blockDim.x;
  for (; i < n; i += st) dst[i] = isbf ? ((const u16*)src)[i] : f2bf(((const float*)src)[i]);
}

__global__ void k_cvt(const void* src, float* dst, long long n, const int* flag) {
  int isbf = *flag;
  long long i = (long long)blockIdx.x * blockDim.x + threadIdx.x;
  long long st = (long long)gridDim.x * blockDim.x;
  for (; i < n; i += st) dst[i] = ldf(src, i, isbf);
}

__global__ void k_emit(const u16* ybuf, const u16* xbuf, void* out,
                       const int* flag, long long ny, long long nt) {
  int isbf = *flag;
  long long i = (long long)blockIdx.x * blockDim.x + threadIdx.x;
  long long st = (long long)gridDim.x * blockDim.x;
  for (; i < nt; i += st) {
    u16 v = (i < ny) ? ybuf[i] : xbuf[i - ny];
    if (isbf) ((u16*)out)[i] = v;
    else      ((float*)out)[i] = bf2f(v);
  }
}

// ---------------- weight transpose+convert: [R][C] raw -> [C][R] bf16 ----------------
__global__ __launch_bounds__(256) void k_wt(const void* src, u16* dst, int R, int C, const int* flag) {
  int isbf = *flag;
  __shared__ u16 t[32][33];
  long long base = (long long)blockIdx.z * R * C;
  int c0 = blockIdx.x * 32, r0 = blockIdx.y * 32;
  int tx = threadIdx.x & 31, ty = threadIdx.x >> 5;
#pragma unroll
  for (int k = 0; k < 4; ++k) {
    int r = r0 + ty + k * 8;
    t[ty + k * 8][tx] = f2bf(ldf(src, base + (long long)r * C + (c0 + tx), isbf));
  }
  __syncthreads();
#pragma unroll
  for (int k = 0; k < 4; ++k) {
    int c = c0 + ty + k * 8;
    dst[base + (long long)c * R + (r0 + tx)] = t[tx][ty + k * 8];
  }
}

// ---------------- bbox cosine-sim + softmax (bf16 out) ----------------
__global__ __launch_bounds__(256) void k_bboxsim(const void* bbox, const int* flag, u16* sim) {
  int isbf = *flag;
  int b = blockIdx.x >> 8, i = blockIdx.x & 255;
  int j = threadIdx.x;
  long long base = (long long)b * LXc * 4;
  float a[4], c[4];
#pragma unroll
  for (int t = 0; t < 4; ++t) {
    a[t] = ldf(bbox, base + (long long)i * 4 + t, isbf);
    c[t] = ldf(bbox, base + (long long)j * 4 + t, isbf);
  }
  float dot = a[0]*c[0] + a[1]*c[1] + a[2]*c[2] + a[3]*c[3];
  float na  = sqrtf(a[0]*a[0] + a[1]*a[1] + a[2]*a[2] + a[3]*a[3]);
  float ncn = sqrtf(c[0]*c[0] + c[1]*c[1] + c[2]*c[2] + c[3]*c[3]);
  float v = dot / (na * ncn);
  __shared__ float r1[4], r2[4];
  float m = v;
  for (int o = 32; o; o >>= 1) m = fmaxf(m, __shfl_xor(m, o));
  if ((threadIdx.x & 63) == 0) r1[threadIdx.x >> 6] = m;
  __syncthreads();
  m = fmaxf(fmaxf(r1[0], r1[1]), fmaxf(r1[2], r1[3]));
  float e = __expf(v - m);
  float s = e;
  for (int o = 32; o; o >>= 1) s += __shfl_xor(s, o);
  if ((threadIdx.x & 63) == 0) r2[threadIdx.x >> 6] = s;
  __syncthreads();
  s = r2[0] + r2[1] + r2[2] + r2[3];
  sim[((long long)b * LXc + i) * LXc + j] = f2bf(e / s);
}

// ---------------- residual + layernorm, vectorized (uint2 = 4 bf16 / lane) ----------------
// 192 threads (3 waves), one row of 768 per block.
__global__ __launch_bounds__(192) void k_lnres4(u16* curb, const u16* delta,
                                                const void* g, long long gOff,
                                                const void* bb, long long bOff,
                                                const int* flag) {
  int isbf = *flag;
  long long row = blockIdx.x;
  u16* xr = curb + row * Dc;
  const u16* dr = delta + row * Dc;
  int t = threadIdx.x;
  union { u16 u[4]; uint2 d; } xa, da;
  xa.d = *(const uint2*)(xr + t * 4);
  da.d = *(const uint2*)(dr + t * 4);
  float v[4];
  float s = 0.f;
#pragma unroll
  for (int i = 0; i < 4; ++i) { v[i] = bf2f(xa.u[i]) + bf2f(da.u[i]); s += v[i]; }
  __shared__ float r1[3], r2[3];
  for (int o = 32; o; o >>= 1) s += __shfl_xor(s, o);
  if ((t & 63) == 0) r1[t >> 6] = s;
  __syncthreads();
  float mean = (r1[0] + r1[1] + r1[2]) * (1.0f / 768.0f);
  float s2 = 0.f;
#pragma unroll
  for (int i = 0; i < 4; ++i) { float d = v[i] - mean; s2 += d * d; }
  for (int o = 32; o; o >>= 1) s2 += __shfl_xor(s2, o);
  if ((t & 63) == 0) r2[t >> 6] = s2;
  __syncthreads();
  float var = (r2[0] + r2[1] + r2[2]) * (1.0f / 768.0f);
  float rstd = rsqrtf(var + 1e-6f);
  union { u16 u[4]; uint2 d; } oa;
#pragma unroll
  for (int i = 0; i < 4; ++i) {
    int c = t * 4 + i;
    float o = ldf(g, gOff + c, isbf) * (v[i] - mean) * rstd + ldf(bb, bOff + c, isbf);
    oa.u[i] = f2bf(o);
  }
  *(uint2*)(xr + t * 4) = oa.d;
}

// ---------------- fused flash attention ----------------
template<int DEC>
__global__ __launch_bounds__(256) void k_attn(const u16* __restrict__ Q,
                                              const u16* __restrict__ Kb,
                                              const u16* __restrict__ Vt,
                                              u16* __restrict__ Out,
                                              int Lq, int Lk) {
  __shared__ __align__(16) u16 Kl[64 * 64];
  __shared__ __align__(16) u16 Vl[64 * 64];
  __shared__ __align__(16) u16 Pl[4][16][72];
  const int tid = threadIdx.x, wid = tid >> 6, lane = tid & 63;
  const int qt = blockIdx.x, h = blockIdx.y, b = blockIdx.z;
  const int q0 = qt * 64 + wid * 16;
  const int rl = lane & 15, sx = lane >> 4;
  const int srow = lane >> 3;
  const int scol8 = ((lane & 7) ^ srow) << 3;

  s16x8 qa[2];
  {
    const u16* qrow = Q + ((long long)b * Lq + q0 + rl) * Dc + h * 64;
    qa[0] = *(const s16x8*)(qrow + sx * 8);
    qa[1] = *(const s16x8*)(qrow + 32 + sx * 8);
  }
  f32x4 o[4] = {};
  float m[4], l[4];
#pragma unroll
  for (int e = 0; e < 4; ++e) { m[e] = -3.0e38f; l[e] = 0.f; }

  const long long kbase = (long long)b * Lk * Dc + h * 64;
  const long long vbase = ((long long)b * Dc + h * 64) * Lk;

  for (int k0 = 0; k0 < Lk; k0 += 64) {
#pragma unroll
    for (int g = 0; g < 2; ++g) {
      int chunk = g * 4 + wid;
      gload16(Kb + kbase + (long long)(k0 + chunk * 8 + srow) * Dc + scol8,
              (char*)Kl + chunk * 1024);
    }
#pragma unroll
    for (int g = 0; g < 2; ++g) {
      int chunk = g * 4 + wid;
      gload16(Vt + vbase + (long long)(chunk * 8 + srow) * Lk + k0 + scol8,
              (char*)Vl + chunk * 1024);
    }
    asm volatile("s_waitcnt vmcnt(0)" ::: "memory");
    barx();

    f32x4 s[4];
#pragma unroll
    for (int n = 0; n < 4; ++n) {
      s16x8 b0 = *(const s16x8*)((char*)Kl + (n * 16 + rl) * 128 + ((sx    ) ^ (rl & 7)) * 16);
      s16x8 b1 = *(const s16x8*)((char*)Kl + (n * 16 + rl) * 128 + ((sx + 4) ^ (rl & 7)) * 16);
      f32x4 acc = {};
      acc = __builtin_amdgcn_mfma_f32_16x16x32_bf16(qa[0], b0, acc, 0, 0, 0);
      acc = __builtin_amdgcn_mfma_f32_16x16x32_bf16(qa[1], b1, acc, 0, 0, 0);
      s[n] = acc;
    }
#pragma unroll
    for (int n = 0; n < 4; ++n)
#pragma unroll
      for (int e = 0; e < 4; ++e) s[n][e] *= 0.125f;

#pragma unroll
    for (int e = 0; e < 4; ++e) {
      float v = fmaxf(fmaxf(s[0][e], s[1][e]), fmaxf(s[2][e], s[3][e]));
      v = fmaxf(v, __shfl_xor(v, 1));
      v = fmaxf(v, __shfl_xor(v, 2));
      v = fmaxf(v, __shfl_xor(v, 4));
      v = fmaxf(v, __shfl_xor(v, 8));
      float mn = fmaxf(m[e], v);
      float alpha = __expf(m[e] - mn);
      m[e] = mn;
      float ls = 0.f;
#pragma unroll
      for (int n = 0; n < 4; ++n) {
        float p = __expf(s[n][e] - mn);
        s[n][e] = p;
        ls += p;
      }
      ls += __shfl_xor(ls, 1);
      ls += __shfl_xor(ls, 2);
      ls += __shfl_xor(ls, 4);
      ls += __shfl_xor(ls, 8);
      l[e] = l[e] * alpha + ls;
#pragma unroll
      for (int n = 0; n < 4; ++n) o[n][e] *= alpha;
    }

#pragma unroll
    for (int e = 0; e < 4; ++e)
#pragma unroll
      for (int n = 0; n < 4; ++n)
        Pl[wid][sx * 4 + e][n * 16 + rl] = f2bf(s[n][e]);
    barx();

    s16x8 pa0 = *(const s16x8*)&Pl[wid][rl][sx * 8];
    s16x8 pa1 = *(const s16x8*)&Pl[wid][rl][32 + sx * 8];
#pragma unroll
    for (int n = 0; n < 4; ++n) {
      s16x8 v0 = *(const s16x8*)((char*)Vl + (n * 16 + rl) * 128 + ((sx    ) ^ (rl & 7)) * 16);
      s16x8 v1 = *(const s16x8*)((char*)Vl + (n * 16 + rl) * 128 + ((sx + 4) ^ (rl & 7)) * 16);
      o[n] = __builtin_amdgcn_mfma_f32_16x16x32_bf16(pa0, v0, o[n], 0, 0, 0);
      o[n] = __builtin_amdgcn_mfma_f32_16x16x32_bf16(pa1, v1, o[n], 0, 0, 0);
    }
    barx();
  }

#pragma unroll
  for (int e = 0; e < 4; ++e) l[e] = 1.0f / l[e];
  if (DEC) {
    u16* Op = Out + ((long long)b * Dc + h * 64) * LXc;
#pragma unroll
    for (int n = 0; n < 4; ++n) {
      union { u16 u[4]; uint2 d; } pk;
#pragma unroll
      for (int e = 0; e < 4; ++e) pk.u[e] = f2bf(o[n][e] * l[e]);
      *(uint2*)&Op[(long long)(n * 16 + rl) * LXc + q0 + sx * 4] = pk.d;
    }
  } else {
    u16* Op = Out + ((long long)b * Lq + q0) * Dc + h * 64;
#pragma unroll
    for (int n = 0; n < 4; ++n)
#pragma unroll
      for (int e = 0; e < 4; ++e)
        Op[(long long)(sx * 4 + e) * Dc + n * 16 + rl] = f2bf(o[n][e] * l[e]);
  }
}

// ---------------- GEMM param block ----------------
struct G2 {
  const u16* A; long long lda, sAb, sAh;
  const u16* W; long long ldw, sWb, sWh;
  const float* bias; long long bOff;
  void* C; long long ldc, sCb, sCh;
  void* Ck; void* Cv; int vSeg;
  int Hdim; float scale; int relu; int Lseq;
};

// ---------------- 128xBN double-buffered MFMA GEMM (T2 swizzle + counted vmcnt) ----------------
// stage(t+1) is issued BEFORE computing tile t; the tile switch waits
// vmcnt(NLD) (= per-wave loads of tile t+1 still in flight) -> staging latency
// hides under MFMA+ds_read. Trailing barrier frees the other buffer.
template<int BM, int BN, int MODE>
__global__ __launch_bounds__(256, 2) void gemm2(G2 p, int M, int N, int K) {
  constexpr int BK = 64;
  constexpr int NLD = BM / 32 + BN / 32;     // gload instrs per wave per tile
  __shared__ __align__(16) u16 Al[2][BM * BK];
  __shared__ __align__(16) u16 Bl[2][BN * BK];
  const int tid = threadIdx.x, wid = tid >> 6, lane = tid & 63;
  const int z = blockIdx.z, zb = z / p.Hdim, zh = z % p.Hdim;
  int bx = blockIdx.x, by = blockIdx.y;
  if (gridDim.z == 1) {
    int gx = gridDim.x, nwg = gx * gridDim.y;
    int orig = by * gx + bx;
    int q = nwg >> 3, r = nwg & 7, xcd = orig & 7, lin = orig >> 3;
    int wg = (xcd < r ? xcd * (q + 1) : r * (q + 1) + (xcd - r) * q) + lin;
    bx = wg % gx; by = wg / gx;
  }
  const u16* A = p.A + (long long)zb * p.sAb + (long long)zh * p.sAh;
  const u16* W = p.W + (long long)zb * p.sWb + (long long)zh * p.sWh;
  const int m0 = by * BM, n0 = bx * BN;
  const int wr = wid >> 1, wc = wid & 1;
  constexpr int FM = BM / 32, FN = BN / 32;
  f32x4 acc[FM][FN] = {};
  const int lr = lane >> 3;                        // row within 8-row chunk
  const int lo = (((lane & 7) ^ lr) << 3) * 2;     // inverse-swizzled source byte off
  const int rl = lane & 15;
  const int sx = lane >> 4;
  const int slotb0 = (((sx + 0) ^ (rl & 7)) << 4); // swizzled read byte off, ks=0
  const int slotb1 = (((sx + 4) ^ (rl & 7)) << 4); // swizzled read byte off, ks=1

  auto stage = [&](int t, int bb) {
    long long k0 = (long long)t * BK;
#pragma unroll
    for (int i = 0; i < FM; ++i) {
      int chunk = wid * FM + i;
      int row = chunk * 8 + lr;
      gload16((const char*)(A + (long long)(m0 + row) * p.lda + k0) + lo,
              (char*)Al[bb] + chunk * 1024);
    }
#pragma unroll
    for (int i = 0; i < FN; ++i) {
      int chunk = wid * FN + i;
      int row = chunk * 8 + lr;
      gload16((const char*)(W + (long long)(n0 + row) * p.ldw + k0) + lo,
              (char*)Bl[bb] + chunk * 1024);
    }
  };

  const int NT = K / BK;
  stage(0, 0);
  for (int t = 0; t < NT; ++t) {
    const int bb = t & 1;
    if (t + 1 < NT) {
      stage(t + 1, bb ^ 1);
      if constexpr (NLD == 8)      asm volatile("s_waitcnt vmcnt(8)" ::: "memory");
      else if constexpr (NLD == 6) asm volatile("s_waitcnt vmcnt(6)" ::: "memory");
      else                         asm volatile("s_waitcnt vmcnt(0)" ::: "memory");
    } else {
      asm volatile("s_waitcnt vmcnt(0)" ::: "memory");
    }
    barx();   // tile t published to all waves
    {
      s16x8 af[FM][2], bfr[FN][2];
#pragma unroll
      for (int i = 0; i < FM; ++i) {
        const char* rbase = (char*)Al[bb] + (wr * (BM / 2) + i * 16 + rl) * 128;
        af[i][0] = *(const s16x8*)(rbase + slotb0);
        af[i][1] = *(const s16x8*)(rbase + slotb1);
      }
#pragma unroll
      for (int j = 0; j < FN; ++j) {
        const char* rbase = (char*)Bl[bb] + (wc * (BN / 2) + j * 16 + rl) * 128;
        bfr[j][0] = *(const s16x8*)(rbase + slotb0);
        bfr[j][1] = *(const s16x8*)(rbase + slotb1);
      }
#pragma unroll
      for (int ks = 0; ks < 2; ++ks)
#pragma unroll
        for (int i = 0; i < FM; ++i)
#pragma unroll
          for (int j = 0; j < FN; ++j)
            acc[i][j] = __builtin_amdgcn_mfma_f32_16x16x32_bf16(af[i][ks], bfr[j][ks], acc[i][j], 0, 0, 0);
    }
    barx();   // all waves done reading tile t -> buffer bb free for t+2
  }

  const int seg = (MODE == 4) ? (n0 / 768) : 0;
#pragma unroll
  for (int j = 0; j < FN; ++j) {
    int col = n0 + wc * (BN / 2) + j * 16 + (lane & 15);
    float bv = p.bias ? p.bias[p.bOff + col] : 0.f;
#pragma unroll
    for (int i = 0; i < FM; ++i) {
      int row0 = m0 + wr * (BM / 2) + i * 16 + (lane >> 4) * 4;
      if (MODE == 0) {
        u16* C = (u16*)p.C + (long long)zb * p.sCb + (long long)zh * p.sCh;
#pragma unroll
        for (int e = 0; e < 4; ++e) {
          float v = acc[i][j][e] * p.scale + bv;
          if (p.relu) v = fmaxf(v, 0.f);
          C[(long long)(row0 + e) * p.ldc + col] = f2bf(v);
        }
      } else {  // MODE 4: segment-routed QKV
        u16* outp = seg == 0 ? (u16*)p.C : (seg == 1 ? (u16*)p.Ck : (u16*)p.Cv);
        int c = col - seg * 768;
        if (seg == p.vSeg) {
          int b = row0 / p.Lseq, l = row0 % p.Lseq;
          union { u16 u[4]; uint2 d; } pk;
#pragma unroll
          for (int e = 0; e < 4; ++e) pk.u[e] = f2bf(acc[i][j][e] + bv);
          *(uint2*)&outp[((long long)b * Dc + c) * p.Lseq + l] = pk.d;
        } else {
#pragma unroll
          for (int e = 0; e < 4; ++e)
            outp[(long long)(row0 + e) * 768 + c] = f2bf(acc[i][j][e] + bv);
        }
      }
    }
  }
}

// ---------------- launch helpers ----------------
template<int BM, int BN, int MODE>
static void run_gemm(const G2& p, int M, int N, int K, int nz, hipStream_t st) {
  dim3 grid(N / BN, M / BM, nz);
  gemm2<BM, BN, MODE><<<grid, 256, 0, st>>>(p, M, N, K);
}

extern "C" void kernel_launch(void* const* d_in, const int* in_sizes, int n_in,
                              void* d_out, int out_size, void* d_ws, size_t ws_size,
                              hipStream_t stream) {
  const void* y_in  = d_in[0];
  const void* x_in  = d_in[1];
  const void* bbox  = d_in[5];
  const void* enc_aw = d_in[6];  const void* enc_ab = d_in[7];
  const void* enc_w1 = d_in[8];  const void* enc_b1 = d_in[9];
  const void* enc_w2 = d_in[10]; const void* enc_b2 = d_in[11];
  const void* enc_lg = d_in[12]; const void* enc_lb = d_in[13];
  const void* dec_aw = d_in[14]; const void* dec_ab = d_in[15];
  const void* dec_w1 = d_in[16]; const void* dec_b1 = d_in[17];
  const void* dec_w2 = d_in[18]; const void* dec_b2 = d_in[19];
  const void* dec_lg = d_in[20]; const void* dec_lb = d_in[21];

  char* base = (char*)d_ws;
  size_t off = 0;
  auto alloc = [&](size_t bytes) { void* p = base + off; off = (off + bytes + 255) & ~(size_t)255; return p; };
  int*  flag = (int*)alloc(256);
  const long long DD = (long long)Dc * Dc;
  const long long DF = (long long)Dc * FFc;
  u16* WencA  = (u16*)alloc(24 * DD * 2);
  u16* WencW1 = (u16*)alloc(6 * DF * 2);
  u16* WencW2 = (u16*)alloc(6 * DF * 2);
  u16* WdecA  = (u16*)alloc(48 * DD * 2);
  u16* WdecW1 = (u16*)alloc(6 * DF * 2);
  u16* WdecW2 = (u16*)alloc(6 * DF * 2);
  float* BencA  = (float*)alloc(24 * Dc * 4);
  float* BencW1 = (float*)alloc(6 * FFc * 4);
  float* BencW2 = (float*)alloc(6 * Dc * 4);
  float* BdecA  = (float*)alloc(48 * Dc * 4);
  float* BdecW1 = (float*)alloc(6 * FFc * 4);
  float* BdecW2 = (float*)alloc(6 * Dc * 4);
  const long long NYt = (long long)NB * LYc * Dc;
  const long long NXt = (long long)NB * LXc * Dc;
  u16*   curb_y = (u16*)alloc(NYt * 2);
  u16*   curb_x = (u16*)alloc(NXt * 2);
  u16*   simb   = (u16*)alloc((long long)NB * LXc * LXc * 2);
  u16*   qbf    = (u16*)alloc(NXt * 2);
  u16*   kbf    = (u16*)alloc(NXt * 2);
  u16*   vT     = (u16*)alloc(NXt * 2);
  u16*   deltab = (u16*)alloc(NXt * 2);
  u16*   aoT    = (u16*)alloc(NXt * 2);
  u16*   ao2    = (u16*)alloc(NXt * 2);
  u16*   ffmid  = (u16*)alloc((long long)NB * LXc * FFc * 2);

  k_detect<<<1, 64, 0, stream>>>((const u16*)y_in, flag);
  k_ingest_b<<<1024, 256, 0, stream>>>(y_in, curb_y, NYt, flag);
  k_ingest_b<<<1024, 256, 0, stream>>>(x_in, curb_x, NXt, flag);
  k_bboxsim<<<NB * LXc, 256, 0, stream>>>(bbox, flag, simb);
  k_wt<<<dim3(Dc/32, Dc/32, 24), 256, 0, stream>>>(enc_aw, WencA, Dc, Dc, flag);
  k_wt<<<dim3(FFc/32, Dc/32, 6), 256, 0, stream>>>(enc_w1, WencW1, Dc, FFc, flag);
  k_wt<<<dim3(Dc/32, FFc/32, 6), 256, 0, stream>>>(enc_w2, WencW2, FFc, Dc, flag);
  k_wt<<<dim3(Dc/32, Dc/32, 48), 256, 0, stream>>>(dec_aw, WdecA, Dc, Dc, flag);
  k_wt<<<dim3(FFc/32, Dc/32, 6), 256, 0, stream>>>(dec_w1, WdecW1, Dc, FFc, flag);
  k_wt<<<dim3(Dc/32, FFc/32, 6), 256, 0, stream>>>(dec_w2, WdecW2, FFc, Dc, flag);
  k_cvt<<<32, 256, 0, stream>>>(enc_ab, BencA, 24 * Dc, flag);
  k_cvt<<<32, 256, 0, stream>>>(enc_b1, BencW1, 6 * FFc, flag);
  k_cvt<<<32, 256, 0, stream>>>(enc_b2, BencW2, 6 * Dc, flag);
  k_cvt<<<32, 256, 0, stream>>>(dec_ab, BdecA, 48 * Dc, flag);
  k_cvt<<<32, 256, 0, stream>>>(dec_b1, BdecW1, 6 * FFc, flag);
  k_cvt<<<32, 256, 0, stream>>>(dec_b2, BdecW2, 6 * Dc, flag);

  // ---- helpers ----
  auto qkv = [&](const u16* A, int M, const u16* Wt, long long wOff,
                 const float* bias, long long bOff, int Lseq) {
    G2 p{}; p.A = A; p.lda = Dc; p.W = Wt + wOff; p.ldw = Dc;
    p.bias = bias; p.bOff = bOff;
    p.C = qbf; p.Ck = kbf; p.Cv = vT; p.vSeg = 2;
    p.Hdim = 1; p.scale = 1.f; p.Lseq = Lseq;
    run_gemm<128, 128, 4>(p, M, 3 * Dc, Dc, 1, stream);
  };
  auto kv = [&](const u16* A, int M, const u16* Wt, long long wOff,
                const float* bias, long long bOff, int Lseq) {
    G2 p{}; p.A = A; p.lda = Dc; p.W = Wt + wOff; p.ldw = Dc;
    p.bias = bias; p.bOff = bOff;
    p.C = kbf; p.Ck = vT; p.vSeg = 1;
    p.Hdim = 1; p.scale = 1.f; p.Lseq = Lseq;
    run_gemm<128, 128, 4>(p, M, 2 * Dc, Dc, 1, stream);
  };
  auto p768 = [&](const u16* A, int M, const u16* Wt, long long wOff,
                  const float* bias, long long bOff, u16* C, int K, int relu) {
    G2 p{}; p.A = A; p.lda = K; p.W = Wt + wOff; p.ldw = K;
    p.bias = bias; p.bOff = bOff; p.C = C; p.ldc = Dc;
    p.Hdim = 1; p.scale = 1.f; p.relu = relu;
    run_gemm<128, 64, 0>(p, M, Dc, K, 1, stream);
  };
  auto ffn1 = [&](const u16* A, int M, const u16* Wt, long long wOff,
                  const float* bias, long long bOff) {
    G2 p{}; p.A = A; p.lda = Dc; p.W = Wt + wOff; p.ldw = Dc;
    p.bias = bias; p.bOff = bOff; p.C = ffmid; p.ldc = FFc;
    p.Hdim = 1; p.scale = 1.f; p.relu = 1;
    run_gemm<128, 128, 0>(p, M, FFc, Dc, 1, stream);
  };
  auto g_rel = [&]() {
    G2 p{}; p.A = simb; p.lda = LXc; p.sAb = (long long)LXc * LXc;
    p.W = aoT; p.ldw = LXc; p.sWb = (long long)Dc * LXc;
    p.C = ao2; p.ldc = Dc; p.sCb = (long long)LXc * Dc;
    p.Hdim = 1; p.scale = 1.f;
    run_gemm<128, 128, 0>(p, LXc, Dc, LXc, NB, stream);
  };

  // ---- encoder (M = 4096) ----
  for (int i = 0; i < 6; ++i) {
    int M = NB * LYc;
    long long wo = (long long)i * 4 * DD, bo = (long long)i * 4 * Dc;
    qkv(curb_y, M, WencA, wo, BencA, bo, LYc);
    k_attn<0><<<dim3(LYc / 64, NH, NB), 256, 0, stream>>>(qbf, kbf, vT, ao2, LYc, LYc);
    p768(ao2, M, WencA, wo + 3 * DD, BencA, bo + 3 * Dc, deltab, Dc, 0);
    k_lnres4<<<M, 192, 0, stream>>>(curb_y, deltab, enc_lg, (long long)(i*2+0)*Dc, enc_lb, (long long)(i*2+0)*Dc, flag);
    ffn1(curb_y, M, WencW1, (long long)i * DF, BencW1, (long long)i * FFc);
    p768(ffmid, M, WencW2, (long long)i * DF, BencW2, (long long)i * Dc, deltab, FFc, 0);
    k_lnres4<<<M, 192, 0, stream>>>(curb_y, deltab, enc_lg, (long long)(i*2+1)*Dc, enc_lb, (long long)(i*2+1)*Dc, flag);
  }

  // ---- decoder (M = 8192) ----
  for (int i = 0; i < 6; ++i) {
    int M = NB * LXc;
    for (int a = 0; a < 2; ++a) {
      long long wo = (long long)(i * 2 + a) * 4 * DD;
      long long bo = (long long)(i * 2 + a) * 4 * Dc;
      int Lk;
      if (a == 0) {
        qkv(curb_x, M, WdecA, wo, BdecA, bo, LXc);
        Lk = LXc;
      } else {
        p768(curb_x, M, WdecA, wo, BdecA, bo, qbf, Dc, 0);
        kv(curb_y, NB * LYc, WdecA, wo + DD, BdecA, bo + Dc, LYc);
        Lk = LYc;
      }
      k_attn<1><<<dim3(LXc / 64, NH, NB), 256, 0, stream>>>(qbf, kbf, vT, aoT, LXc, Lk);
      g_rel();
      p768(ao2, M, WdecA, wo + 3 * DD, BdecA, bo + 3 * Dc, deltab, Dc, 0);
      k_lnres4<<<M, 192, 0, stream>>>(curb_x, deltab, dec_lg, (long long)(i*3+a)*Dc, dec_lb, (long long)(i*3+a)*Dc, flag);
    }
    ffn1(curb_x, M, WdecW1, (long long)i * DF, BdecW1, (long long)i * FFc);
    p768(ffmid, M, WdecW2, (long long)i * DF, BdecW2, (long long)i * Dc, deltab, FFc, 0);
    k_lnres4<<<M, 192, 0, stream>>>(curb_x, deltab, dec_lg, (long long)(i*3+2)*Dc, dec_lb, (long long)(i*3+2)*Dc, flag);
  }

  k_emit<<<2048, 256, 0, stream>>>(curb_y, curb_x, d_out, flag, NYt, NYt + NXt);
}

// Round 10
// 3287.112 us; speedup vs baseline: 1.0454x; 1.0454x over previous
//
#include <hip/hip_runtime.h>

#define DEV __device__ __forceinline__

constexpr int NB  = 32;
constexpr int LXc = 256;
constexpr int LYc = 128;
constexpr int Dc  = 768;
constexpr int NH  = 12;
constexpr int FFc = 3072;

typedef unsigned short u16;
typedef float f32x4 __attribute__((ext_vector_type(4)));
typedef short s16x8 __attribute__((ext_vector_type(8)));

DEV u16 f2bf(float f) {
  unsigned u = __float_as_uint(f);
  u += 0x7FFFu + ((u >> 16) & 1u);
  return (u16)(u >> 16);
}
DEV float bf2f(u16 w) { return __uint_as_float(((unsigned)w) << 16); }
DEV float ldf(const void* p, long long i, int isbf) {
  return isbf ? bf2f(((const u16*)p)[i]) : ((const float*)p)[i];
}

DEV void gload16(const void* g, void* l) {
  __builtin_amdgcn_global_load_lds(
      (const __attribute__((address_space(1))) void*)g,
      (__attribute__((address_space(3))) void*)l, 16, 0, 0);
}
DEV void barx() {
  asm volatile("" ::: "memory");
  __builtin_amdgcn_s_barrier();
  asm volatile("" ::: "memory");
}

// ---------------- dtype detection ----------------
__global__ void k_detect(const u16* y, int* flag) {
  if (threadIdx.x == 0) {
    int cnt = 0;
    for (int i = 0; i < 256; ++i) {
      u16 w = y[i];
      int e = (w >> 7) & 0xFF;
      if (e == 0 || (e >= 112 && e <= 140)) cnt++;
    }
    *flag = (cnt >= 200) ? 1 : 0;
  }
}

// raw -> bf16 stream
__global__ void k_ingest_b(const void* src, u16* dst, long long n, const int* flag) {
  int isbf = *flag;
  long long i = (long long)blockIdx.x * blockDim.x + threadIdx.x;
  long long st = (long long)gridDim.x * blockDim.x;
  for (; i < n; i += st) dst[i] = isbf ? ((const u16*)src)[i] : f2bf(((const float*)src)[i]);
}

__global__ void k_cvt(const void* src, float* dst, long long n, const int* flag) {
  int isbf = *flag;
  long long i = (long long)blockIdx.x * blockDim.x + threadIdx.x;
  long long st = (long long)gridDim.x * blockDim.x;
  for (; i < n; i += st) dst[i] = ldf(src, i, isbf);
}

__global__ void k_emit(const u16* ybuf, const u16* xbuf, void* out,
                       const int* flag, long long ny, long long nt) {
  int isbf = *flag;
  long long i = (long long)blockIdx.x * blockDim.x + threadIdx.x;
  long long st = (long long)gridDim.x * blockDim.x;
  for (; i < nt; i += st) {
    u16 v = (i < ny) ? ybuf[i] : xbuf[i - ny];
    if (isbf) ((u16*)out)[i] = v;
    else      ((float*)out)[i] = bf2f(v);
  }
}

// ---------------- weight transpose+convert: [R][C] raw -> [C][R] bf16 ----------------
__global__ __launch_bounds__(256) void k_wt(const void* src, u16* dst, int R, int C, const int* flag) {
  int isbf = *flag;
  __shared__ u16 t[32][33];
  long long base = (long long)blockIdx.z * R * C;
  int c0 = blockIdx.x * 32, r0 = blockIdx.y * 32;
  int tx = threadIdx.x & 31, ty = threadIdx.x >> 5;
#pragma unroll
  for (int k = 0; k < 4; ++k) {
    int r = r0 + ty + k * 8;
    t[ty + k * 8][tx] = f2bf(ldf(src, base + (long long)r * C + (c0 + tx), isbf));
  }
  __syncthreads();
#pragma unroll
  for (int k = 0; k < 4; ++k) {
    int c = c0 + ty + k * 8;
    dst[base + (long long)c * R + (r0 + tx)] = t[tx][ty + k * 8];
  }
}

// ---------------- bbox cosine-sim + softmax (bf16 out) ----------------
__global__ __launch_bounds__(256) void k_bboxsim(const void* bbox, const int* flag, u16* sim) {
  int isbf = *flag;
  int b = blockIdx.x >> 8, i = blockIdx.x & 255;
  int j = threadIdx.x;
  long long base = (long long)b * LXc * 4;
  float a[4], c[4];
#pragma unroll
  for (int t = 0; t < 4; ++t) {
    a[t] = ldf(bbox, base + (long long)i * 4 + t, isbf);
    c[t] = ldf(bbox, base + (long long)j * 4 + t, isbf);
  }
  float dot = a[0]*c[0] + a[1]*c[1] + a[2]*c[2] + a[3]*c[3];
  float na  = sqrtf(a[0]*a[0] + a[1]*a[1] + a[2]*a[2] + a[3]*a[3]);
  float ncn = sqrtf(c[0]*c[0] + c[1]*c[1] + c[2]*c[2] + c[3]*c[3]);
  float v = dot / (na * ncn);
  __shared__ float r1[4], r2[4];
  float m = v;
  for (int o = 32; o; o >>= 1) m = fmaxf(m, __shfl_xor(m, o));
  if ((threadIdx.x & 63) == 0) r1[threadIdx.x >> 6] = m;
  __syncthreads();
  m = fmaxf(fmaxf(r1[0], r1[1]), fmaxf(r1[2], r1[3]));
  float e = __expf(v - m);
  float s = e;
  for (int o = 32; o; o >>= 1) s += __shfl_xor(s, o);
  if ((threadIdx.x & 63) == 0) r2[threadIdx.x >> 6] = s;
  __syncthreads();
  s = r2[0] + r2[1] + r2[2] + r2[3];
  sim[((long long)b * LXc + i) * LXc + j] = f2bf(e / s);
}

// ---------------- residual + layernorm: wave-per-row, no LDS, no barriers ----------------
// 256 threads = 4 waves, each wave owns one row of 768 (3 x uint2 = 12 bf16 / lane).
__global__ __launch_bounds__(256) void k_lnres5(u16* curb, const u16* delta,
                                                const void* g, long long gOff,
                                                const void* bb, long long bOff,
                                                const int* flag) {
  int isbf = *flag;
  const int lane = threadIdx.x & 63;
  long long row = (long long)blockIdx.x * 4 + (threadIdx.x >> 6);
  u16* xr = curb + row * Dc;
  const u16* dr = delta + row * Dc;
  float v[12];
  float s = 0.f;
#pragma unroll
  for (int c = 0; c < 3; ++c) {
    union { u16 u[4]; uint2 d; } xa, da;
    xa.d = *(const uint2*)(xr + c * 256 + lane * 4);
    da.d = *(const uint2*)(dr + c * 256 + lane * 4);
#pragma unroll
    for (int i = 0; i < 4; ++i) {
      float t = bf2f(xa.u[i]) + bf2f(da.u[i]);
      v[c * 4 + i] = t;
      s += t;
    }
  }
  for (int o = 32; o; o >>= 1) s += __shfl_xor(s, o);
  float mean = s * (1.0f / 768.0f);
  float s2 = 0.f;
#pragma unroll
  for (int i = 0; i < 12; ++i) { float d = v[i] - mean; s2 += d * d; }
  for (int o = 32; o; o >>= 1) s2 += __shfl_xor(s2, o);
  float rstd = rsqrtf(s2 * (1.0f / 768.0f) + 1e-6f);
#pragma unroll
  for (int c = 0; c < 3; ++c) {
    union { u16 u[4]; uint2 d; } oa;
#pragma unroll
    for (int i = 0; i < 4; ++i) {
      int col = c * 256 + lane * 4 + i;
      float o = ldf(g, gOff + col, isbf) * (v[c * 4 + i] - mean) * rstd + ldf(bb, bOff + col, isbf);
      oa.u[i] = f2bf(o);
    }
    *(uint2*)(xr + c * 256 + lane * 4) = oa.d;
  }
}

// ---------------- fused flash attention ----------------
template<int DEC>
__global__ __launch_bounds__(256) void k_attn(const u16* __restrict__ Q,
                                              const u16* __restrict__ Kb,
                                              const u16* __restrict__ Vt,
                                              u16* __restrict__ Out,
                                              int Lq, int Lk) {
  __shared__ __align__(16) u16 Kl[64 * 64];
  __shared__ __align__(16) u16 Vl[64 * 64];
  __shared__ __align__(16) u16 Pl[4][16][72];
  const int tid = threadIdx.x, wid = tid >> 6, lane = tid & 63;
  const int qt = blockIdx.x, h = blockIdx.y, b = blockIdx.z;
  const int q0 = qt * 64 + wid * 16;
  const int rl = lane & 15, sx = lane >> 4;
  const int srow = lane >> 3;
  const int scol8 = ((lane & 7) ^ srow) << 3;

  s16x8 qa[2];
  {
    const u16* qrow = Q + ((long long)b * Lq + q0 + rl) * Dc + h * 64;
    qa[0] = *(const s16x8*)(qrow + sx * 8);
    qa[1] = *(const s16x8*)(qrow + 32 + sx * 8);
  }
  f32x4 o[4] = {};
  float m[4], l[4];
#pragma unroll
  for (int e = 0; e < 4; ++e) { m[e] = -3.0e38f; l[e] = 0.f; }

  const long long kbase = (long long)b * Lk * Dc + h * 64;
  const long long vbase = ((long long)b * Dc + h * 64) * Lk;

  for (int k0 = 0; k0 < Lk; k0 += 64) {
#pragma unroll
    for (int g = 0; g < 2; ++g) {
      int chunk = g * 4 + wid;
      gload16(Kb + kbase + (long long)(k0 + chunk * 8 + srow) * Dc + scol8,
              (char*)Kl + chunk * 1024);
    }
#pragma unroll
    for (int g = 0; g < 2; ++g) {
      int chunk = g * 4 + wid;
      gload16(Vt + vbase + (long long)(chunk * 8 + srow) * Lk + k0 + scol8,
              (char*)Vl + chunk * 1024);
    }
    asm volatile("s_waitcnt vmcnt(0)" ::: "memory");
    barx();

    f32x4 s[4];
#pragma unroll
    for (int n = 0; n < 4; ++n) {
      s16x8 b0 = *(const s16x8*)((char*)Kl + (n * 16 + rl) * 128 + ((sx    ) ^ (rl & 7)) * 16);
      s16x8 b1 = *(const s16x8*)((char*)Kl + (n * 16 + rl) * 128 + ((sx + 4) ^ (rl & 7)) * 16);
      f32x4 acc = {};
      acc = __builtin_amdgcn_mfma_f32_16x16x32_bf16(qa[0], b0, acc, 0, 0, 0);
      acc = __builtin_amdgcn_mfma_f32_16x16x32_bf16(qa[1], b1, acc, 0, 0, 0);
      s[n] = acc;
    }
#pragma unroll
    for (int n = 0; n < 4; ++n)
#pragma unroll
      for (int e = 0; e < 4; ++e) s[n][e] *= 0.125f;

#pragma unroll
    for (int e = 0; e < 4; ++e) {
      float v = fmaxf(fmaxf(s[0][e], s[1][e]), fmaxf(s[2][e], s[3][e]));
      v = fmaxf(v, __shfl_xor(v, 1));
      v = fmaxf(v, __shfl_xor(v, 2));
      v = fmaxf(v, __shfl_xor(v, 4));
      v = fmaxf(v, __shfl_xor(v, 8));
      float mn = fmaxf(m[e], v);
      float alpha = __expf(m[e] - mn);
      m[e] = mn;
      float ls = 0.f;
#pragma unroll
      for (int n = 0; n < 4; ++n) {
        float p = __expf(s[n][e] - mn);
        s[n][e] = p;
        ls += p;
      }
      ls += __shfl_xor(ls, 1);
      ls += __shfl_xor(ls, 2);
      ls += __shfl_xor(ls, 4);
      ls += __shfl_xor(ls, 8);
      l[e] = l[e] * alpha + ls;
#pragma unroll
      for (int n = 0; n < 4; ++n) o[n][e] *= alpha;
    }

#pragma unroll
    for (int e = 0; e < 4; ++e)
#pragma unroll
      for (int n = 0; n < 4; ++n)
        Pl[wid][sx * 4 + e][n * 16 + rl] = f2bf(s[n][e]);
    barx();

    s16x8 pa0 = *(const s16x8*)&Pl[wid][rl][sx * 8];
    s16x8 pa1 = *(const s16x8*)&Pl[wid][rl][32 + sx * 8];
#pragma unroll
    for (int n = 0; n < 4; ++n) {
      s16x8 v0 = *(const s16x8*)((char*)Vl + (n * 16 + rl) * 128 + ((sx    ) ^ (rl & 7)) * 16);
      s16x8 v1 = *(const s16x8*)((char*)Vl + (n * 16 + rl) * 128 + ((sx + 4) ^ (rl & 7)) * 16);
      o[n] = __builtin_amdgcn_mfma_f32_16x16x32_bf16(pa0, v0, o[n], 0, 0, 0);
      o[n] = __builtin_amdgcn_mfma_f32_16x16x32_bf16(pa1, v1, o[n], 0, 0, 0);
    }
    barx();
  }

#pragma unroll
  for (int e = 0; e < 4; ++e) l[e] = 1.0f / l[e];
  if (DEC) {
    u16* Op = Out + ((long long)b * Dc + h * 64) * LXc;
#pragma unroll
    for (int n = 0; n < 4; ++n) {
      union { u16 u[4]; uint2 d; } pk;
#pragma unroll
      for (int e = 0; e < 4; ++e) pk.u[e] = f2bf(o[n][e] * l[e]);
      *(uint2*)&Op[(long long)(n * 16 + rl) * LXc + q0 + sx * 4] = pk.d;
    }
  } else {
    u16* Op = Out + ((long long)b * Lq + q0) * Dc + h * 64;
#pragma unroll
    for (int n = 0; n < 4; ++n)
#pragma unroll
      for (int e = 0; e < 4; ++e)
        Op[(long long)(sx * 4 + e) * Dc + n * 16 + rl] = f2bf(o[n][e] * l[e]);
  }
}

// ---------------- GEMM param block ----------------
struct G2 {
  const u16* A; long long lda, sAb, sAh;
  const u16* W; long long ldw, sWb, sWh;
  const float* bias; long long bOff;
  void* C; long long ldc, sCb, sCh;
  void* Ck; void* Cv; int vSeg;
  int Hdim; float scale; int relu; int Lseq;
};

// ---------------- 128xBN 2-phase MFMA GEMM with T2 LDS swizzle (R8 structure) ----------------
// Single-buffered: max residency (5-6 blocks/CU) beats intra-block pipelining here
// (R9 post-mortem: dbuf halved blocks/CU, net -8.5%).
template<int BM, int BN, int MODE>
__global__ __launch_bounds__(256, 2) void gemm2(G2 p, int M, int N, int K) {
  constexpr int BK = 64;
  __shared__ __align__(16) u16 Al[BM * BK];
  __shared__ __align__(16) u16 Bl[BN * BK];
  const int tid = threadIdx.x, wid = tid >> 6, lane = tid & 63;
  const int z = blockIdx.z, zb = z / p.Hdim, zh = z % p.Hdim;
  int bx = blockIdx.x, by = blockIdx.y;
  if (gridDim.z == 1) {
    int gx = gridDim.x, nwg = gx * gridDim.y;
    int orig = by * gx + bx;
    int q = nwg >> 3, r = nwg & 7, xcd = orig & 7, lin = orig >> 3;
    int wg = (xcd < r ? xcd * (q + 1) : r * (q + 1) + (xcd - r) * q) + lin;
    bx = wg % gx; by = wg / gx;
  }
  const u16* A = p.A + (long long)zb * p.sAb + (long long)zh * p.sAh;
  const u16* W = p.W + (long long)zb * p.sWb + (long long)zh * p.sWh;
  const int m0 = by * BM, n0 = bx * BN;
  const int wr = wid >> 1, wc = wid & 1;
  constexpr int FM = BM / 32, FN = BN / 32;
  f32x4 acc[FM][FN] = {};
  const int lr = lane >> 3;                        // row within 8-row chunk
  const int lo = (((lane & 7) ^ lr) << 3) * 2;     // inverse-swizzled source byte off
  const int rl = lane & 15;
  const int sx = lane >> 4;
  const int slotb0 = (((sx + 0) ^ (rl & 7)) << 4); // swizzled read byte off, ks=0
  const int slotb1 = (((sx + 4) ^ (rl & 7)) << 4); // swizzled read byte off, ks=1

  for (int k0 = 0; k0 < K; k0 += BK) {
#pragma unroll
    for (int i = 0; i < FM; ++i) {
      int chunk = wid * FM + i;
      int row = chunk * 8 + lr;
      gload16((const char*)(A + (long long)(m0 + row) * p.lda + k0) + lo,
              (char*)Al + chunk * 1024);
    }
#pragma unroll
    for (int i = 0; i < FN; ++i) {
      int chunk = wid * FN + i;
      int row = chunk * 8 + lr;
      gload16((const char*)(W + (long long)(n0 + row) * p.ldw + k0) + lo,
              (char*)Bl + chunk * 1024);
    }
    __syncthreads();
    {
      s16x8 af[FM][2], bfr[FN][2];
#pragma unroll
      for (int i = 0; i < FM; ++i) {
        const char* rbase = (char*)Al + (wr * (BM / 2) + i * 16 + rl) * 128;
        af[i][0] = *(const s16x8*)(rbase + slotb0);
        af[i][1] = *(const s16x8*)(rbase + slotb1);
      }
#pragma unroll
      for (int j = 0; j < FN; ++j) {
        const char* rbase = (char*)Bl + (wc * (BN / 2) + j * 16 + rl) * 128;
        bfr[j][0] = *(const s16x8*)(rbase + slotb0);
        bfr[j][1] = *(const s16x8*)(rbase + slotb1);
      }
#pragma unroll
      for (int ks = 0; ks < 2; ++ks)
#pragma unroll
        for (int i = 0; i < FM; ++i)
#pragma unroll
          for (int j = 0; j < FN; ++j)
            acc[i][j] = __builtin_amdgcn_mfma_f32_16x16x32_bf16(af[i][ks], bfr[j][ks], acc[i][j], 0, 0, 0);
    }
    __syncthreads();
  }

  const int seg = (MODE == 4) ? (n0 / 768) : 0;
#pragma unroll
  for (int j = 0; j < FN; ++j) {
    int col = n0 + wc * (BN / 2) + j * 16 + (lane & 15);
    float bv = p.bias ? p.bias[p.bOff + col] : 0.f;
#pragma unroll
    for (int i = 0; i < FM; ++i) {
      int row0 = m0 + wr * (BM / 2) + i * 16 + (lane >> 4) * 4;
      if (MODE == 0) {
        u16* C = (u16*)p.C + (long long)zb * p.sCb + (long long)zh * p.sCh;
#pragma unroll
        for (int e = 0; e < 4; ++e) {
          float v = acc[i][j][e] * p.scale + bv;
          if (p.relu) v = fmaxf(v, 0.f);
          C[(long long)(row0 + e) * p.ldc + col] = f2bf(v);
        }
      } else {  // MODE 4: segment-routed QKV
        u16* outp = seg == 0 ? (u16*)p.C : (seg == 1 ? (u16*)p.Ck : (u16*)p.Cv);
        int c = col - seg * 768;
        if (seg == p.vSeg) {
          int b = row0 / p.Lseq, l = row0 % p.Lseq;
          union { u16 u[4]; uint2 d; } pk;
#pragma unroll
          for (int e = 0; e < 4; ++e) pk.u[e] = f2bf(acc[i][j][e] + bv);
          *(uint2*)&outp[((long long)b * Dc + c) * p.Lseq + l] = pk.d;
        } else {
#pragma unroll
          for (int e = 0; e < 4; ++e)
            outp[(long long)(row0 + e) * 768 + c] = f2bf(acc[i][j][e] + bv);
        }
      }
    }
  }
}

// ---------------- launch helpers ----------------
template<int BM, int BN, int MODE>
static void run_gemm(const G2& p, int M, int N, int K, int nz, hipStream_t st) {
  dim3 grid(N / BN, M / BM, nz);
  gemm2<BM, BN, MODE><<<grid, 256, 0, st>>>(p, M, N, K);
}

extern "C" void kernel_launch(void* const* d_in, const int* in_sizes, int n_in,
                              void* d_out, int out_size, void* d_ws, size_t ws_size,
                              hipStream_t stream) {
  const void* y_in  = d_in[0];
  const void* x_in  = d_in[1];
  const void* bbox  = d_in[5];
  const void* enc_aw = d_in[6];  const void* enc_ab = d_in[7];
  const void* enc_w1 = d_in[8];  const void* enc_b1 = d_in[9];
  const void* enc_w2 = d_in[10]; const void* enc_b2 = d_in[11];
  const void* enc_lg = d_in[12]; const void* enc_lb = d_in[13];
  const void* dec_aw = d_in[14]; const void* dec_ab = d_in[15];
  const void* dec_w1 = d_in[16]; const void* dec_b1 = d_in[17];
  const void* dec_w2 = d_in[18]; const void* dec_b2 = d_in[19];
  const void* dec_lg = d_in[20]; const void* dec_lb = d_in[21];

  char* base = (char*)d_ws;
  size_t off = 0;
  auto alloc = [&](size_t bytes) { void* p = base + off; off = (off + bytes + 255) & ~(size_t)255; return p; };
  int*  flag = (int*)alloc(256);
  const long long DD = (long long)Dc * Dc;
  const long long DF = (long long)Dc * FFc;
  u16* WencA  = (u16*)alloc(24 * DD * 2);
  u16* WencW1 = (u16*)alloc(6 * DF * 2);
  u16* WencW2 = (u16*)alloc(6 * DF * 2);
  u16* WdecA  = (u16*)alloc(48 * DD * 2);
  u16* WdecW1 = (u16*)alloc(6 * DF * 2);
  u16* WdecW2 = (u16*)alloc(6 * DF * 2);
  float* BencA  = (float*)alloc(24 * Dc * 4);
  float* BencW1 = (float*)alloc(6 * FFc * 4);
  float* BencW2 = (float*)alloc(6 * Dc * 4);
  float* BdecA  = (float*)alloc(48 * Dc * 4);
  float* BdecW1 = (float*)alloc(6 * FFc * 4);
  float* BdecW2 = (float*)alloc(6 * Dc * 4);
  const long long NYt = (long long)NB * LYc * Dc;
  const long long NXt = (long long)NB * LXc * Dc;
  u16*   curb_y = (u16*)alloc(NYt * 2);
  u16*   curb_x = (u16*)alloc(NXt * 2);
  u16*   simb   = (u16*)alloc((long long)NB * LXc * LXc * 2);
  u16*   qbf    = (u16*)alloc(NXt * 2);
  u16*   kbf    = (u16*)alloc(NXt * 2);
  u16*   vT     = (u16*)alloc(NXt * 2);
  u16*   deltab = (u16*)alloc(NXt * 2);
  u16*   aoT    = (u16*)alloc(NXt * 2);
  u16*   ao2    = (u16*)alloc(NXt * 2);
  u16*   ffmid  = (u16*)alloc((long long)NB * LXc * FFc * 2);

  k_detect<<<1, 64, 0, stream>>>((const u16*)y_in, flag);
  k_ingest_b<<<1024, 256, 0, stream>>>(y_in, curb_y, NYt, flag);
  k_ingest_b<<<1024, 256, 0, stream>>>(x_in, curb_x, NXt, flag);
  k_bboxsim<<<NB * LXc, 256, 0, stream>>>(bbox, flag, simb);
  k_wt<<<dim3(Dc/32, Dc/32, 24), 256, 0, stream>>>(enc_aw, WencA, Dc, Dc, flag);
  k_wt<<<dim3(FFc/32, Dc/32, 6), 256, 0, stream>>>(enc_w1, WencW1, Dc, FFc, flag);
  k_wt<<<dim3(Dc/32, FFc/32, 6), 256, 0, stream>>>(enc_w2, WencW2, FFc, Dc, flag);
  k_wt<<<dim3(Dc/32, Dc/32, 48), 256, 0, stream>>>(dec_aw, WdecA, Dc, Dc, flag);
  k_wt<<<dim3(FFc/32, Dc/32, 6), 256, 0, stream>>>(dec_w1, WdecW1, Dc, FFc, flag);
  k_wt<<<dim3(Dc/32, FFc/32, 6), 256, 0, stream>>>(dec_w2, WdecW2, FFc, Dc, flag);
  k_cvt<<<32, 256, 0, stream>>>(enc_ab, BencA, 24 * Dc, flag);
  k_cvt<<<32, 256, 0, stream>>>(enc_b1, BencW1, 6 * FFc, flag);
  k_cvt<<<32, 256, 0, stream>>>(enc_b2, BencW2, 6 * Dc, flag);
  k_cvt<<<32, 256, 0, stream>>>(dec_ab, BdecA, 48 * Dc, flag);
  k_cvt<<<32, 256, 0, stream>>>(dec_b1, BdecW1, 6 * FFc, flag);
  k_cvt<<<32, 256, 0, stream>>>(dec_b2, BdecW2, 6 * Dc, flag);

  // ---- helpers ----
  auto qkv = [&](const u16* A, int M, const u16* Wt, long long wOff,
                 const float* bias, long long bOff, int Lseq) {
    G2 p{}; p.A = A; p.lda = Dc; p.W = Wt + wOff; p.ldw = Dc;
    p.bias = bias; p.bOff = bOff;
    p.C = qbf; p.Ck = kbf; p.Cv = vT; p.vSeg = 2;
    p.Hdim = 1; p.scale = 1.f; p.Lseq = Lseq;
    run_gemm<128, 128, 4>(p, M, 3 * Dc, Dc, 1, stream);
  };
  auto kv = [&](const u16* A, int M, const u16* Wt, long long wOff,
                const float* bias, long long bOff, int Lseq) {
    G2 p{}; p.A = A; p.lda = Dc; p.W = Wt + wOff; p.ldw = Dc;
    p.bias = bias; p.bOff = bOff;
    p.C = kbf; p.Ck = vT; p.vSeg = 1;
    p.Hdim = 1; p.scale = 1.f; p.Lseq = Lseq;
    run_gemm<128, 128, 4>(p, M, 2 * Dc, Dc, 1, stream);
  };
  auto p768 = [&](const u16* A, int M, const u16* Wt, long long wOff,
                  const float* bias, long long bOff, u16* C, int K, int relu) {
    G2 p{}; p.A = A; p.lda = K; p.W = Wt + wOff; p.ldw = K;
    p.bias = bias; p.bOff = bOff; p.C = C; p.ldc = Dc;
    p.Hdim = 1; p.scale = 1.f; p.relu = relu;
    run_gemm<128, 64, 0>(p, M, Dc, K, 1, stream);
  };
  auto ffn1 = [&](const u16* A, int M, const u16* Wt, long long wOff,
                  const float* bias, long long bOff) {
    G2 p{}; p.A = A; p.lda = Dc; p.W = Wt + wOff; p.ldw = Dc;
    p.bias = bias; p.bOff = bOff; p.C = ffmid; p.ldc = FFc;
    p.Hdim = 1; p.scale = 1.f; p.relu = 1;
    run_gemm<128, 128, 0>(p, M, FFc, Dc, 1, stream);
  };
  auto g_rel = [&]() {
    G2 p{}; p.A = simb; p.lda = LXc; p.sAb = (long long)LXc * LXc;
    p.W = aoT; p.ldw = LXc; p.sWb = (long long)Dc * LXc;
    p.C = ao2; p.ldc = Dc; p.sCb = (long long)LXc * Dc;
    p.Hdim = 1; p.scale = 1.f;
    run_gemm<128, 128, 0>(p, LXc, Dc, LXc, NB, stream);
  };

  // ---- encoder (M = 4096) ----
  for (int i = 0; i < 6; ++i) {
    int M = NB * LYc;
    long long wo = (long long)i * 4 * DD, bo = (long long)i * 4 * Dc;
    qkv(curb_y, M, WencA, wo, BencA, bo, LYc);
    k_attn<0><<<dim3(LYc / 64, NH, NB), 256, 0, stream>>>(qbf, kbf, vT, ao2, LYc, LYc);
    p768(ao2, M, WencA, wo + 3 * DD, BencA, bo + 3 * Dc, deltab, Dc, 0);
    k_lnres5<<<M / 4, 256, 0, stream>>>(curb_y, deltab, enc_lg, (long long)(i*2+0)*Dc, enc_lb, (long long)(i*2+0)*Dc, flag);
    ffn1(curb_y, M, WencW1, (long long)i * DF, BencW1, (long long)i * FFc);
    p768(ffmid, M, WencW2, (long long)i * DF, BencW2, (long long)i * Dc, deltab, FFc, 0);
    k_lnres5<<<M / 4, 256, 0, stream>>>(curb_y, deltab, enc_lg, (long long)(i*2+1)*Dc, enc_lb, (long long)(i*2+1)*Dc, flag);
  }

  // ---- decoder (M = 8192) ----
  for (int i = 0; i < 6; ++i) {
    int M = NB * LXc;
    for (int a = 0; a < 2; ++a) {
      long long wo = (long long)(i * 2 + a) * 4 * DD;
      long long bo = (long long)(i * 2 + a) * 4 * Dc;
      int Lk;
      if (a == 0) {
        qkv(curb_x, M, WdecA, wo, BdecA, bo, LXc);
        Lk = LXc;
      } else {
        p768(curb_x, M, WdecA, wo, BdecA, bo, qbf, Dc, 0);
        kv(curb_y, NB * LYc, WdecA, wo + DD, BdecA, bo + Dc, LYc);
        Lk = LYc;
      }
      k_attn<1><<<dim3(LXc / 64, NH, NB), 256, 0, stream>>>(qbf, kbf, vT, aoT, LXc, Lk);
      g_rel();
      p768(ao2, M, WdecA, wo + 3 * DD, BdecA, bo + 3 * Dc, deltab, Dc, 0);
      k_lnres5<<<M / 4, 256, 0, stream>>>(curb_x, deltab, dec_lg, (long long)(i*3+a)*Dc, dec_lb, (long long)(i*3+a)*Dc, flag);
    }
    ffn1(curb_x, M, WdecW1, (long long)i * DF, BdecW1, (long long)i * FFc);
    p768(ffmid, M, WdecW2, (long long)i * DF, BdecW2, (long long)i * Dc, deltab, FFc, 0);
    k_lnres5<<<M / 4, 256, 0, stream>>>(curb_x, deltab, dec_lg, (long long)(i*3+2)*Dc, dec_lb, (long long)(i*3+2)*Dc, flag);
  }

  k_emit<<<2048, 256, 0, stream>>>(curb_y, curb_x, d_out, flag, NYt, NYt + NXt);
}

// Round 11
// 3233.959 us; speedup vs baseline: 1.0626x; 1.0164x over previous
//
#include <hip/hip_runtime.h>

#define DEV __device__ __forceinline__

constexpr int NB  = 32;
constexpr int LXc = 256;
constexpr int LYc = 128;
constexpr int Dc  = 768;
constexpr int NH  = 12;
constexpr int FFc = 3072;

typedef unsigned short u16;
typedef float f32x4 __attribute__((ext_vector_type(4)));
typedef short s16x8 __attribute__((ext_vector_type(8)));

DEV u16 f2bf(float f) {
  unsigned u = __float_as_uint(f);
  u += 0x7FFFu + ((u >> 16) & 1u);
  return (u16)(u >> 16);
}
DEV float bf2f(u16 w) { return __uint_as_float(((unsigned)w) << 16); }
DEV float ldf(const void* p, long long i, int isbf) {
  return isbf ? bf2f(((const u16*)p)[i]) : ((const float*)p)[i];
}

DEV void gload16(const void* g, void* l) {
  __builtin_amdgcn_global_load_lds(
      (const __attribute__((address_space(1))) void*)g,
      (__attribute__((address_space(3))) void*)l, 16, 0, 0);
}
DEV void barx() {
  asm volatile("" ::: "memory");
  __builtin_amdgcn_s_barrier();
  asm volatile("" ::: "memory");
}

// ---------------- dtype detection ----------------
__global__ void k_detect(const u16* y, int* flag) {
  if (threadIdx.x == 0) {
    int cnt = 0;
    for (int i = 0; i < 256; ++i) {
      u16 w = y[i];
      int e = (w >> 7) & 0xFF;
      if (e == 0 || (e >= 112 && e <= 140)) cnt++;
    }
    *flag = (cnt >= 200) ? 1 : 0;
  }
}

// raw -> bf16 stream
__global__ void k_ingest_b(const void* src, u16* dst, long long n, const int* flag) {
  int isbf = *flag;
  long long i = (long long)blockIdx.x * blockDim.x + threadIdx.x;
  long long st = (long long)gridDim.x * blockDim.x;
  for (; i < n; i += st) dst[i] = isbf ? ((const u16*)src)[i] : f2bf(((const float*)src)[i]);
}

__global__ void k_cvt(const void* src, float* dst, long long n, const int* flag) {
  int isbf = *flag;
  long long i = (long long)blockIdx.x * blockDim.x + threadIdx.x;
  long long st = (long long)gridDim.x * blockDim.x;
  for (; i < n; i += st) dst[i] = ldf(src, i, isbf);
}

__global__ void k_emit(const u16* ybuf, const u16* xbuf, void* out,
                       const int* flag, long long ny, long long nt) {
  int isbf = *flag;
  long long i = (long long)blockIdx.x * blockDim.x + threadIdx.x;
  long long st = (long long)gridDim.x * blockDim.x;
  for (; i < nt; i += st) {
    u16 v = (i < ny) ? ybuf[i] : xbuf[i - ny];
    if (isbf) ((u16*)out)[i] = v;
    else      ((float*)out)[i] = bf2f(v);
  }
}

// ---------------- weight transpose+convert: [R][C] raw -> [C][R] bf16 ----------------
__global__ __launch_bounds__(256) void k_wt(const void* src, u16* dst, int R, int C, const int* flag) {
  int isbf = *flag;
  __shared__ u16 t[32][33];
  long long base = (long long)blockIdx.z * R * C;
  int c0 = blockIdx.x * 32, r0 = blockIdx.y * 32;
  int tx = threadIdx.x & 31, ty = threadIdx.x >> 5;
#pragma unroll
  for (int k = 0; k < 4; ++k) {
    int r = r0 + ty + k * 8;
    t[ty + k * 8][tx] = f2bf(ldf(src, base + (long long)r * C + (c0 + tx), isbf));
  }
  __syncthreads();
#pragma unroll
  for (int k = 0; k < 4; ++k) {
    int c = c0 + ty + k * 8;
    dst[base + (long long)c * R + (r0 + tx)] = t[tx][ty + k * 8];
  }
}

// ---------------- bbox cosine-sim + softmax (bf16 out) ----------------
__global__ __launch_bounds__(256) void k_bboxsim(const void* bbox, const int* flag, u16* sim) {
  int isbf = *flag;
  int b = blockIdx.x >> 8, i = blockIdx.x & 255;
  int j = threadIdx.x;
  long long base = (long long)b * LXc * 4;
  float a[4], c[4];
#pragma unroll
  for (int t = 0; t < 4; ++t) {
    a[t] = ldf(bbox, base + (long long)i * 4 + t, isbf);
    c[t] = ldf(bbox, base + (long long)j * 4 + t, isbf);
  }
  float dot = a[0]*c[0] + a[1]*c[1] + a[2]*c[2] + a[3]*c[3];
  float na  = sqrtf(a[0]*a[0] + a[1]*a[1] + a[2]*a[2] + a[3]*a[3]);
  float ncn = sqrtf(c[0]*c[0] + c[1]*c[1] + c[2]*c[2] + c[3]*c[3]);
  float v = dot / (na * ncn);
  __shared__ float r1[4], r2[4];
  float m = v;
  for (int o = 32; o; o >>= 1) m = fmaxf(m, __shfl_xor(m, o));
  if ((threadIdx.x & 63) == 0) r1[threadIdx.x >> 6] = m;
  __syncthreads();
  m = fmaxf(fmaxf(r1[0], r1[1]), fmaxf(r1[2], r1[3]));
  float e = __expf(v - m);
  float s = e;
  for (int o = 32; o; o >>= 1) s += __shfl_xor(s, o);
  if ((threadIdx.x & 63) == 0) r2[threadIdx.x >> 6] = s;
  __syncthreads();
  s = r2[0] + r2[1] + r2[2] + r2[3];
  sim[((long long)b * LXc + i) * LXc + j] = f2bf(e / s);
}

// ---------------- residual + layernorm, vectorized (uint2 = 4 bf16 / lane) ----------------
// 192 threads (3 waves), one row of 768 per block. (R9-proven-correct variant.)
__global__ __launch_bounds__(192) void k_lnres4(u16* curb, const u16* delta,
                                                const void* g, long long gOff,
                                                const void* bb, long long bOff,
                                                const int* flag) {
  int isbf = *flag;
  long long row = blockIdx.x;
  u16* xr = curb + row * Dc;
  const u16* dr = delta + row * Dc;
  int t = threadIdx.x;
  union { u16 u[4]; uint2 d; } xa, da;
  xa.d = *(const uint2*)(xr + t * 4);
  da.d = *(const uint2*)(dr + t * 4);
  float v[4];
  float s = 0.f;
#pragma unroll
  for (int i = 0; i < 4; ++i) { v[i] = bf2f(xa.u[i]) + bf2f(da.u[i]); s += v[i]; }
  __shared__ float r1[3], r2[3];
  for (int o = 32; o; o >>= 1) s += __shfl_xor(s, o);
  if ((t & 63) == 0) r1[t >> 6] = s;
  __syncthreads();
  float mean = (r1[0] + r1[1] + r1[2]) * (1.0f / 768.0f);
  float s2 = 0.f;
#pragma unroll
  for (int i = 0; i < 4; ++i) { float d = v[i] - mean; s2 += d * d; }
  for (int o = 32; o; o >>= 1) s2 += __shfl_xor(s2, o);
  if ((t & 63) == 0) r2[t >> 6] = s2;
  __syncthreads();
  float var = (r2[0] + r2[1] + r2[2]) * (1.0f / 768.0f);
  float rstd = rsqrtf(var + 1e-6f);
  union { u16 u[4]; uint2 d; } oa;
#pragma unroll
  for (int i = 0; i < 4; ++i) {
    int c = t * 4 + i;
    float o = ldf(g, gOff + c, isbf) * (v[i] - mean) * rstd + ldf(bb, bOff + c, isbf);
    oa.u[i] = f2bf(o);
  }
  *(uint2*)(xr + t * 4) = oa.d;
}

// ---------------- fused flash attention ----------------
template<int DEC>
__global__ __launch_bounds__(256) void k_attn(const u16* __restrict__ Q,
                                              const u16* __restrict__ Kb,
                                              const u16* __restrict__ Vt,
                                              u16* __restrict__ Out,
                                              int Lq, int Lk) {
  __shared__ __align__(16) u16 Kl[64 * 64];
  __shared__ __align__(16) u16 Vl[64 * 64];
  __shared__ __align__(16) u16 Pl[4][16][72];
  const int tid = threadIdx.x, wid = tid >> 6, lane = tid & 63;
  const int qt = blockIdx.x, h = blockIdx.y, b = blockIdx.z;
  const int q0 = qt * 64 + wid * 16;
  const int rl = lane & 15, sx = lane >> 4;
  const int srow = lane >> 3;
  const int scol8 = ((lane & 7) ^ srow) << 3;

  s16x8 qa[2];
  {
    const u16* qrow = Q + ((long long)b * Lq + q0 + rl) * Dc + h * 64;
    qa[0] = *(const s16x8*)(qrow + sx * 8);
    qa[1] = *(const s16x8*)(qrow + 32 + sx * 8);
  }
  f32x4 o[4] = {};
  float m[4], l[4];
#pragma unroll
  for (int e = 0; e < 4; ++e) { m[e] = -3.0e38f; l[e] = 0.f; }

  const long long kbase = (long long)b * Lk * Dc + h * 64;
  const long long vbase = ((long long)b * Dc + h * 64) * Lk;

  for (int k0 = 0; k0 < Lk; k0 += 64) {
#pragma unroll
    for (int g = 0; g < 2; ++g) {
      int chunk = g * 4 + wid;
      gload16(Kb + kbase + (long long)(k0 + chunk * 8 + srow) * Dc + scol8,
              (char*)Kl + chunk * 1024);
    }
#pragma unroll
    for (int g = 0; g < 2; ++g) {
      int chunk = g * 4 + wid;
      gload16(Vt + vbase + (long long)(chunk * 8 + srow) * Lk + k0 + scol8,
              (char*)Vl + chunk * 1024);
    }
    asm volatile("s_waitcnt vmcnt(0)" ::: "memory");
    barx();

    f32x4 s[4];
#pragma unroll
    for (int n = 0; n < 4; ++n) {
      s16x8 b0 = *(const s16x8*)((char*)Kl + (n * 16 + rl) * 128 + ((sx    ) ^ (rl & 7)) * 16);
      s16x8 b1 = *(const s16x8*)((char*)Kl + (n * 16 + rl) * 128 + ((sx + 4) ^ (rl & 7)) * 16);
      f32x4 acc = {};
      acc = __builtin_amdgcn_mfma_f32_16x16x32_bf16(qa[0], b0, acc, 0, 0, 0);
      acc = __builtin_amdgcn_mfma_f32_16x16x32_bf16(qa[1], b1, acc, 0, 0, 0);
      s[n] = acc;
    }
#pragma unroll
    for (int n = 0; n < 4; ++n)
#pragma unroll
      for (int e = 0; e < 4; ++e) s[n][e] *= 0.125f;

#pragma unroll
    for (int e = 0; e < 4; ++e) {
      float v = fmaxf(fmaxf(s[0][e], s[1][e]), fmaxf(s[2][e], s[3][e]));
      v = fmaxf(v, __shfl_xor(v, 1));
      v = fmaxf(v, __shfl_xor(v, 2));
      v = fmaxf(v, __shfl_xor(v, 4));
      v = fmaxf(v, __shfl_xor(v, 8));
      float mn = fmaxf(m[e], v);
      float alpha = __expf(m[e] - mn);
      m[e] = mn;
      float ls = 0.f;
#pragma unroll
      for (int n = 0; n < 4; ++n) {
        float p = __expf(s[n][e] - mn);
        s[n][e] = p;
        ls += p;
      }
      ls += __shfl_xor(ls, 1);
      ls += __shfl_xor(ls, 2);
      ls += __shfl_xor(ls, 4);
      ls += __shfl_xor(ls, 8);
      l[e] = l[e] * alpha + ls;
#pragma unroll
      for (int n = 0; n < 4; ++n) o[n][e] *= alpha;
    }

#pragma unroll
    for (int e = 0; e < 4; ++e)
#pragma unroll
      for (int n = 0; n < 4; ++n)
        Pl[wid][sx * 4 + e][n * 16 + rl] = f2bf(s[n][e]);
    barx();

    s16x8 pa0 = *(const s16x8*)&Pl[wid][rl][sx * 8];
    s16x8 pa1 = *(const s16x8*)&Pl[wid][rl][32 + sx * 8];
#pragma unroll
    for (int n = 0; n < 4; ++n) {
      s16x8 v0 = *(const s16x8*)((char*)Vl + (n * 16 + rl) * 128 + ((sx    ) ^ (rl & 7)) * 16);
      s16x8 v1 = *(const s16x8*)((char*)Vl + (n * 16 + rl) * 128 + ((sx + 4) ^ (rl & 7)) * 16);
      o[n] = __builtin_amdgcn_mfma_f32_16x16x32_bf16(pa0, v0, o[n], 0, 0, 0);
      o[n] = __builtin_amdgcn_mfma_f32_16x16x32_bf16(pa1, v1, o[n], 0, 0, 0);
    }
    barx();
  }

#pragma unroll
  for (int e = 0; e < 4; ++e) l[e] = 1.0f / l[e];
  if (DEC) {
    u16* Op = Out + ((long long)b * Dc + h * 64) * LXc;
#pragma unroll
    for (int n = 0; n < 4; ++n) {
      union { u16 u[4]; uint2 d; } pk;
#pragma unroll
      for (int e = 0; e < 4; ++e) pk.u[e] = f2bf(o[n][e] * l[e]);
      *(uint2*)&Op[(long long)(n * 16 + rl) * LXc + q0 + sx * 4] = pk.d;
    }
  } else {
    u16* Op = Out + ((long long)b * Lq + q0) * Dc + h * 64;
#pragma unroll
    for (int n = 0; n < 4; ++n)
#pragma unroll
      for (int e = 0; e < 4; ++e)
        Op[(long long)(sx * 4 + e) * Dc + n * 16 + rl] = f2bf(o[n][e] * l[e]);
  }
}

// ---------------- GEMM param block ----------------
struct G2 {
  const u16* A; long long lda, sAb, sAh;
  const u16* W; long long ldw, sWb, sWh;
  const float* bias; long long bOff;
  void* C; long long ldc, sCb, sCh;
  void* Ck; void* Cv; int vSeg;
  int Hdim; float scale; int relu; int Lseq;
};

// ---------------- BMxBN 2-phase MFMA GEMM with T2 LDS swizzle (R8 structure) ----------------
// Single-buffered: max residency beats intra-block pipelining here (R9 post-mortem).
template<int BM, int BN, int MODE>
__global__ __launch_bounds__(256, 2) void gemm2(G2 p, int M, int N, int K) {
  constexpr int BK = 64;
  __shared__ __align__(16) u16 Al[BM * BK];
  __shared__ __align__(16) u16 Bl[BN * BK];
  const int tid = threadIdx.x, wid = tid >> 6, lane = tid & 63;
  const int z = blockIdx.z, zb = z / p.Hdim, zh = z % p.Hdim;
  int bx = blockIdx.x, by = blockIdx.y;
  if (gridDim.z == 1) {
    int gx = gridDim.x, nwg = gx * gridDim.y;
    int orig = by * gx + bx;
    int q = nwg >> 3, r = nwg & 7, xcd = orig & 7, lin = orig >> 3;
    int wg = (xcd < r ? xcd * (q + 1) : r * (q + 1) + (xcd - r) * q) + lin;
    bx = wg % gx; by = wg / gx;
  }
  const u16* A = p.A + (long long)zb * p.sAb + (long long)zh * p.sAh;
  const u16* W = p.W + (long long)zb * p.sWb + (long long)zh * p.sWh;
  const int m0 = by * BM, n0 = bx * BN;
  const int wr = wid >> 1, wc = wid & 1;
  constexpr int FM = BM / 32, FN = BN / 32;
  f32x4 acc[FM][FN] = {};
  const int lr = lane >> 3;                        // row within 8-row chunk
  const int lo = (((lane & 7) ^ lr) << 3) * 2;     // inverse-swizzled source byte off
  const int rl = lane & 15;
  const int sx = lane >> 4;
  const int slotb0 = (((sx + 0) ^ (rl & 7)) << 4); // swizzled read byte off, ks=0
  const int slotb1 = (((sx + 4) ^ (rl & 7)) << 4); // swizzled read byte off, ks=1

  for (int k0 = 0; k0 < K; k0 += BK) {
#pragma unroll
    for (int i = 0; i < FM; ++i) {
      int chunk = wid * FM + i;
      int row = chunk * 8 + lr;
      gload16((const char*)(A + (long long)(m0 + row) * p.lda + k0) + lo,
              (char*)Al + chunk * 1024);
    }
#pragma unroll
    for (int i = 0; i < FN; ++i) {
      int chunk = wid * FN + i;
      int row = chunk * 8 + lr;
      gload16((const char*)(W + (long long)(n0 + row) * p.ldw + k0) + lo,
              (char*)Bl + chunk * 1024);
    }
    __syncthreads();
    {
      s16x8 af[FM][2], bfr[FN][2];
#pragma unroll
      for (int i = 0; i < FM; ++i) {
        const char* rbase = (char*)Al + (wr * (BM / 2) + i * 16 + rl) * 128;
        af[i][0] = *(const s16x8*)(rbase + slotb0);
        af[i][1] = *(const s16x8*)(rbase + slotb1);
      }
#pragma unroll
      for (int j = 0; j < FN; ++j) {
        const char* rbase = (char*)Bl + (wc * (BN / 2) + j * 16 + rl) * 128;
        bfr[j][0] = *(const s16x8*)(rbase + slotb0);
        bfr[j][1] = *(const s16x8*)(rbase + slotb1);
      }
#pragma unroll
      for (int ks = 0; ks < 2; ++ks)
#pragma unroll
        for (int i = 0; i < FM; ++i)
#pragma unroll
          for (int j = 0; j < FN; ++j)
            acc[i][j] = __builtin_amdgcn_mfma_f32_16x16x32_bf16(af[i][ks], bfr[j][ks], acc[i][j], 0, 0, 0);
    }
    __syncthreads();
  }

  const int seg = (MODE == 4) ? (n0 / 768) : 0;
#pragma unroll
  for (int j = 0; j < FN; ++j) {
    int col = n0 + wc * (BN / 2) + j * 16 + (lane & 15);
    float bv = p.bias ? p.bias[p.bOff + col] : 0.f;
#pragma unroll
    for (int i = 0; i < FM; ++i) {
      int row0 = m0 + wr * (BM / 2) + i * 16 + (lane >> 4) * 4;
      if (MODE == 0) {
        u16* C = (u16*)p.C + (long long)zb * p.sCb + (long long)zh * p.sCh;
#pragma unroll
        for (int e = 0; e < 4; ++e) {
          float v = acc[i][j][e] * p.scale + bv;
          if (p.relu) v = fmaxf(v, 0.f);
          C[(long long)(row0 + e) * p.ldc + col] = f2bf(v);
        }
      } else {  // MODE 4: segment-routed QKV
        u16* outp = seg == 0 ? (u16*)p.C : (seg == 1 ? (u16*)p.Ck : (u16*)p.Cv);
        int c = col - seg * 768;
        if (seg == p.vSeg) {
          int b = row0 / p.Lseq, l = row0 % p.Lseq;
          union { u16 u[4]; uint2 d; } pk;
#pragma unroll
          for (int e = 0; e < 4; ++e) pk.u[e] = f2bf(acc[i][j][e] + bv);
          *(uint2*)&outp[((long long)b * Dc + c) * p.Lseq + l] = pk.d;
        } else {
#pragma unroll
          for (int e = 0; e < 4; ++e)
            outp[(long long)(row0 + e) * 768 + c] = f2bf(acc[i][j][e] + bv);
        }
      }
    }
  }
}

// ---------------- launch helpers ----------------
template<int BM, int BN, int MODE>
static void run_gemm(const G2& p, int M, int N, int K, int nz, hipStream_t st) {
  dim3 grid(N / BN, M / BM, nz);
  gemm2<BM, BN, MODE><<<grid, 256, 0, st>>>(p, M, N, K);
}

extern "C" void kernel_launch(void* const* d_in, const int* in_sizes, int n_in,
                              void* d_out, int out_size, void* d_ws, size_t ws_size,
                              hipStream_t stream) {
  const void* y_in  = d_in[0];
  const void* x_in  = d_in[1];
  const void* bbox  = d_in[5];
  const void* enc_aw = d_in[6];  const void* enc_ab = d_in[7];
  const void* enc_w1 = d_in[8];  const void* enc_b1 = d_in[9];
  const void* enc_w2 = d_in[10]; const void* enc_b2 = d_in[11];
  const void* enc_lg = d_in[12]; const void* enc_lb = d_in[13];
  const void* dec_aw = d_in[14]; const void* dec_ab = d_in[15];
  const void* dec_w1 = d_in[16]; const void* dec_b1 = d_in[17];
  const void* dec_w2 = d_in[18]; const void* dec_b2 = d_in[19];
  const void* dec_lg = d_in[20]; const void* dec_lb = d_in[21];

  char* base = (char*)d_ws;
  size_t off = 0;
  auto alloc = [&](size_t bytes) { void* p = base + off; off = (off + bytes + 255) & ~(size_t)255; return p; };
  int*  flag = (int*)alloc(256);
  const long long DD = (long long)Dc * Dc;
  const long long DF = (long long)Dc * FFc;
  u16* WencA  = (u16*)alloc(24 * DD * 2);
  u16* WencW1 = (u16*)alloc(6 * DF * 2);
  u16* WencW2 = (u16*)alloc(6 * DF * 2);
  u16* WdecA  = (u16*)alloc(48 * DD * 2);
  u16* WdecW1 = (u16*)alloc(6 * DF * 2);
  u16* WdecW2 = (u16*)alloc(6 * DF * 2);
  float* BencA  = (float*)alloc(24 * Dc * 4);
  float* BencW1 = (float*)alloc(6 * FFc * 4);
  float* BencW2 = (float*)alloc(6 * Dc * 4);
  float* BdecA  = (float*)alloc(48 * Dc * 4);
  float* BdecW1 = (float*)alloc(6 * FFc * 4);
  float* BdecW2 = (float*)alloc(6 * Dc * 4);
  const long long NYt = (long long)NB * LYc * Dc;
  const long long NXt = (long long)NB * LXc * Dc;
  u16*   curb_y = (u16*)alloc(NYt * 2);
  u16*   curb_x = (u16*)alloc(NXt * 2);
  u16*   simb   = (u16*)alloc((long long)NB * LXc * LXc * 2);
  u16*   qbf    = (u16*)alloc(NXt * 2);
  u16*   kbf    = (u16*)alloc(NXt * 2);
  u16*   vT     = (u16*)alloc(NXt * 2);
  u16*   deltab = (u16*)alloc(NXt * 2);
  u16*   aoT    = (u16*)alloc(NXt * 2);
  u16*   ao2    = (u16*)alloc(NXt * 2);
  u16*   ffmid  = (u16*)alloc((long long)NB * LXc * FFc * 2);

  k_detect<<<1, 64, 0, stream>>>((const u16*)y_in, flag);
  k_ingest_b<<<1024, 256, 0, stream>>>(y_in, curb_y, NYt, flag);
  k_ingest_b<<<1024, 256, 0, stream>>>(x_in, curb_x, NXt, flag);
  k_bboxsim<<<NB * LXc, 256, 0, stream>>>(bbox, flag, simb);
  k_wt<<<dim3(Dc/32, Dc/32, 24), 256, 0, stream>>>(enc_aw, WencA, Dc, Dc, flag);
  k_wt<<<dim3(FFc/32, Dc/32, 6), 256, 0, stream>>>(enc_w1, WencW1, Dc, FFc, flag);
  k_wt<<<dim3(Dc/32, FFc/32, 6), 256, 0, stream>>>(enc_w2, WencW2, FFc, Dc, flag);
  k_wt<<<dim3(Dc/32, Dc/32, 48), 256, 0, stream>>>(dec_aw, WdecA, Dc, Dc, flag);
  k_wt<<<dim3(FFc/32, Dc/32, 6), 256, 0, stream>>>(dec_w1, WdecW1, Dc, FFc, flag);
  k_wt<<<dim3(Dc/32, FFc/32, 6), 256, 0, stream>>>(dec_w2, WdecW2, FFc, Dc, flag);
  k_cvt<<<32, 256, 0, stream>>>(enc_ab, BencA, 24 * Dc, flag);
  k_cvt<<<32, 256, 0, stream>>>(enc_b1, BencW1, 6 * FFc, flag);
  k_cvt<<<32, 256, 0, stream>>>(enc_b2, BencW2, 6 * Dc, flag);
  k_cvt<<<32, 256, 0, stream>>>(dec_ab, BdecA, 48 * Dc, flag);
  k_cvt<<<32, 256, 0, stream>>>(dec_b1, BdecW1, 6 * FFc, flag);
  k_cvt<<<32, 256, 0, stream>>>(dec_b2, BdecW2, 6 * Dc, flag);

  // ---- helpers (tile shapes: >= 3 blocks/CU where possible, minimal tail) ----
  auto qkv = [&](const u16* A, int M, const u16* Wt, long long wOff,
                 const float* bias, long long bOff, int Lseq) {
    G2 p{}; p.A = A; p.lda = Dc; p.W = Wt + wOff; p.ldw = Dc;
    p.bias = bias; p.bOff = bOff;
    p.C = qbf; p.Ck = kbf; p.Cv = vT; p.vSeg = 2;
    p.Hdim = 1; p.scale = 1.f; p.Lseq = Lseq;
    run_gemm<128, 128, 4>(p, M, 3 * Dc, Dc, 1, stream);   // enc 576 / dec 1152
  };
  auto kv = [&](const u16* A, int M, const u16* Wt, long long wOff,
                const float* bias, long long bOff, int Lseq) {
    G2 p{}; p.A = A; p.lda = Dc; p.W = Wt + wOff; p.ldw = Dc;
    p.bias = bias; p.bOff = bOff;
    p.C = kbf; p.Ck = vT; p.vSeg = 1;
    p.Hdim = 1; p.scale = 1.f; p.Lseq = Lseq;
    run_gemm<64, 128, 4>(p, M, 2 * Dc, Dc, 1, stream);    // 768 blocks (was 384)
  };
  auto p768 = [&](const u16* A, int M, const u16* Wt, long long wOff,
                  const float* bias, long long bOff, u16* C, int K, int relu) {
    G2 p{}; p.A = A; p.lda = K; p.W = Wt + wOff; p.ldw = K;
    p.bias = bias; p.bOff = bOff; p.C = C; p.ldc = Dc;
    p.Hdim = 1; p.scale = 1.f; p.relu = relu;
    if (M == NB * LXc) run_gemm<128, 64, 0>(p, M, Dc, K, 1, stream); // dec: 768 blocks
    else               run_gemm<64, 64, 0>(p, M, Dc, K, 1, stream);  // enc: 768 blocks (was 384)
  };
  auto ffn1 = [&](const u16* A, int M, const u16* Wt, long long wOff,
                  const float* bias, long long bOff) {
    G2 p{}; p.A = A; p.lda = Dc; p.W = Wt + wOff; p.ldw = Dc;
    p.bias = bias; p.bOff = bOff; p.C = ffmid; p.ldc = FFc;
    p.Hdim = 1; p.scale = 1.f; p.relu = 1;
    run_gemm<128, 128, 0>(p, M, FFc, Dc, 1, stream);      // enc 768 / dec 1536
  };
  auto g_rel = [&]() {
    G2 p{}; p.A = simb; p.lda = LXc; p.sAb = (long long)LXc * LXc;
    p.W = aoT; p.ldw = LXc; p.sWb = (long long)Dc * LXc;
    p.C = ao2; p.ldc = Dc; p.sCb = (long long)LXc * Dc;
    p.Hdim = 1; p.scale = 1.f;
    run_gemm<128, 128, 0>(p, LXc, Dc, LXc, NB, stream);
  };

  // ---- encoder (M = 4096) ----
  for (int i = 0; i < 6; ++i) {
    int M = NB * LYc;
    long long wo = (long long)i * 4 * DD, bo = (long long)i * 4 * Dc;
    qkv(curb_y, M, WencA, wo, BencA, bo, LYc);
    k_attn<0><<<dim3(LYc / 64, NH, NB), 256, 0, stream>>>(qbf, kbf, vT, ao2, LYc, LYc);
    p768(ao2, M, WencA, wo + 3 * DD, BencA, bo + 3 * Dc, deltab, Dc, 0);
    k_lnres4<<<M, 192, 0, stream>>>(curb_y, deltab, enc_lg, (long long)(i*2+0)*Dc, enc_lb, (long long)(i*2+0)*Dc, flag);
    ffn1(curb_y, M, WencW1, (long long)i * DF, BencW1, (long long)i * FFc);
    p768(ffmid, M, WencW2, (long long)i * DF, BencW2, (long long)i * Dc, deltab, FFc, 0);
    k_lnres4<<<M, 192, 0, stream>>>(curb_y, deltab, enc_lg, (long long)(i*2+1)*Dc, enc_lb, (long long)(i*2+1)*Dc, flag);
  }

  // ---- decoder (M = 8192) ----
  for (int i = 0; i < 6; ++i) {
    int M = NB * LXc;
    for (int a = 0; a < 2; ++a) {
      long long wo = (long long)(i * 2 + a) * 4 * DD;
      long long bo = (long long)(i * 2 + a) * 4 * Dc;
      int Lk;
      if (a == 0) {
        qkv(curb_x, M, WdecA, wo, BdecA, bo, LXc);
        Lk = LXc;
      } else {
        p768(curb_x, M, WdecA, wo, BdecA, bo, qbf, Dc, 0);
        kv(curb_y, NB * LYc, WdecA, wo + DD, BdecA, bo + Dc, LYc);
        Lk = LYc;
      }
      k_attn<1><<<dim3(LXc / 64, NH, NB), 256, 0, stream>>>(qbf, kbf, vT, aoT, LXc, Lk);
      g_rel();
      p768(ao2, M, WdecA, wo + 3 * DD, BdecA, bo + 3 * Dc, deltab, Dc, 0);
      k_lnres4<<<M, 192, 0, stream>>>(curb_x, deltab, dec_lg, (long long)(i*3+a)*Dc, dec_lb, (long long)(i*3+a)*Dc, flag);
    }
    ffn1(curb_x, M, WdecW1, (long long)i * DF, BdecW1, (long long)i * FFc);
    p768(ffmid, M, WdecW2, (long long)i * DF, BdecW2, (long long)i * Dc, deltab, FFc, 0);
    k_lnres4<<<M, 192, 0, stream>>>(curb_x, deltab, dec_lg, (long long)(i*3+2)*Dc, dec_lb, (long long)(i*3+2)*Dc, flag);
  }

  k_emit<<<2048, 256, 0, stream>>>(curb_y, curb_x, d_out, flag, NYt, NYt + NXt);
}

// Round 12
// 3112.936 us; speedup vs baseline: 1.1039x; 1.0389x over previous
//
#include <hip/hip_runtime.h>

#define DEV __device__ __forceinline__

constexpr int NB  = 32;
constexpr int LXc = 256;
constexpr int LYc = 128;
constexpr int Dc  = 768;
constexpr int NH  = 12;
constexpr int FFc = 3072;

typedef unsigned short u16;
typedef float f32x4 __attribute__((ext_vector_type(4)));
typedef short s16x8 __attribute__((ext_vector_type(8)));

DEV u16 f2bf(float f) {
  unsigned u = __float_as_uint(f);
  u += 0x7FFFu + ((u >> 16) & 1u);
  return (u16)(u >> 16);
}
DEV float bf2f(u16 w) { return __uint_as_float(((unsigned)w) << 16); }
DEV float ldf(const void* p, long long i, int isbf) {
  return isbf ? bf2f(((const u16*)p)[i]) : ((const float*)p)[i];
}

DEV void gload16(const void* g, void* l) {
  __builtin_amdgcn_global_load_lds(
      (const __attribute__((address_space(1))) void*)g,
      (__attribute__((address_space(3))) void*)l, 16, 0, 0);
}
DEV void barx() {
  asm volatile("" ::: "memory");
  __builtin_amdgcn_s_barrier();
  asm volatile("" ::: "memory");
}

// ---------------- dtype detection ----------------
__global__ void k_detect(const u16* y, int* flag) {
  if (threadIdx.x == 0) {
    int cnt = 0;
    for (int i = 0; i < 256; ++i) {
      u16 w = y[i];
      int e = (w >> 7) & 0xFF;
      if (e == 0 || (e >= 112 && e <= 140)) cnt++;
    }
    *flag = (cnt >= 200) ? 1 : 0;
  }
}

// raw -> bf16 stream, vectorized 4 elems/lane
__global__ void k_ingest_b4(const void* src, u16* dst, long long n4, const int* flag) {
  int isbf = *flag;
  long long i = (long long)blockIdx.x * blockDim.x + threadIdx.x;
  long long st = (long long)gridDim.x * blockDim.x;
  for (; i < n4; i += st) {
    union { u16 u[4]; uint2 d; } v;
    if (isbf) v.d = ((const uint2*)src)[i];
    else {
      float4 f = ((const float4*)src)[i];
      v.u[0] = f2bf(f.x); v.u[1] = f2bf(f.y); v.u[2] = f2bf(f.z); v.u[3] = f2bf(f.w);
    }
    ((uint2*)dst)[i] = v.d;
  }
}

__global__ void k_cvt(const void* src, float* dst, long long n, const int* flag) {
  int isbf = *flag;
  long long i = (long long)blockIdx.x * blockDim.x + threadIdx.x;
  long long st = (long long)gridDim.x * blockDim.x;
  for (; i < n; i += st) dst[i] = ldf(src, i, isbf);
}

// vectorized emit, 4 elems/lane
__global__ void k_emit4(const u16* ybuf, const u16* xbuf, void* out,
                        const int* flag, long long ny4, long long nt4) {
  int isbf = *flag;
  long long i = (long long)blockIdx.x * blockDim.x + threadIdx.x;
  long long st = (long long)gridDim.x * blockDim.x;
  for (; i < nt4; i += st) {
    union { u16 u[4]; uint2 d; } v;
    v.d = (i < ny4) ? ((const uint2*)ybuf)[i] : ((const uint2*)xbuf)[i - ny4];
    if (isbf) ((uint2*)out)[i] = v.d;
    else {
      float4 f;
      f.x = bf2f(v.u[0]); f.y = bf2f(v.u[1]); f.z = bf2f(v.u[2]); f.w = bf2f(v.u[3]);
      ((float4*)out)[i] = f;
    }
  }
}

// ---------------- vectorized weight transpose+convert: [R][C] raw -> [C][R] bf16 ----------------
// 64x64 tile, 256 threads; uint2/float4 loads, uint2 stores (8-16 B/lane).
__global__ __launch_bounds__(256) void k_wt2(const void* src, u16* dst, int R, int C, const int* flag) {
  int isbf = *flag;
  __shared__ u16 t[64][72];
  long long base = (long long)blockIdx.z * R * C;
  int c0 = blockIdx.x * 64, r0 = blockIdx.y * 64;
  int tr = threadIdx.x >> 4;            // 0..15
  int tc4 = (threadIdx.x & 15) * 4;     // 0,4,..,60
#pragma unroll
  for (int k = 0; k < 4; ++k) {
    int r = tr + k * 16;
    union { u16 u[4]; uint2 d; } v;
    if (isbf) {
      v.d = *(const uint2*)((const u16*)src + base + (long long)(r0 + r) * C + c0 + tc4);
    } else {
      float4 f = *(const float4*)((const float*)src + base + (long long)(r0 + r) * C + c0 + tc4);
      v.u[0] = f2bf(f.x); v.u[1] = f2bf(f.y); v.u[2] = f2bf(f.z); v.u[3] = f2bf(f.w);
    }
    *(uint2*)&t[r][tc4] = v.d;
  }
  __syncthreads();
#pragma unroll
  for (int k = 0; k < 4; ++k) {
    int c = tr + k * 16;
    union { u16 u[4]; uint2 d; } v;
#pragma unroll
    for (int j = 0; j < 4; ++j) v.u[j] = t[tc4 + j][c];
    *(uint2*)&dst[base + (long long)(c0 + c) * R + r0 + tc4] = v.d;
  }
}

// ---------------- bbox cosine-sim + softmax (bf16 out) ----------------
__global__ __launch_bounds__(256) void k_bboxsim(const void* bbox, const int* flag, u16* sim) {
  int isbf = *flag;
  int b = blockIdx.x >> 8, i = blockIdx.x & 255;
  int j = threadIdx.x;
  long long base = (long long)b * LXc * 4;
  float a[4], c[4];
#pragma unroll
  for (int t = 0; t < 4; ++t) {
    a[t] = ldf(bbox, base + (long long)i * 4 + t, isbf);
    c[t] = ldf(bbox, base + (long long)j * 4 + t, isbf);
  }
  float dot = a[0]*c[0] + a[1]*c[1] + a[2]*c[2] + a[3]*c[3];
  float na  = sqrtf(a[0]*a[0] + a[1]*a[1] + a[2]*a[2] + a[3]*a[3]);
  float ncn = sqrtf(c[0]*c[0] + c[1]*c[1] + c[2]*c[2] + c[3]*c[3]);
  float v = dot / (na * ncn);
  __shared__ float r1[4], r2[4];
  float m = v;
  for (int o = 32; o; o >>= 1) m = fmaxf(m, __shfl_xor(m, o));
  if ((threadIdx.x & 63) == 0) r1[threadIdx.x >> 6] = m;
  __syncthreads();
  m = fmaxf(fmaxf(r1[0], r1[1]), fmaxf(r1[2], r1[3]));
  float e = __expf(v - m);
  float s = e;
  for (int o = 32; o; o >>= 1) s += __shfl_xor(s, o);
  if ((threadIdx.x & 63) == 0) r2[threadIdx.x >> 6] = s;
  __syncthreads();
  s = r2[0] + r2[1] + r2[2] + r2[3];
  sim[((long long)b * LXc + i) * LXc + j] = f2bf(e / s);
}

// ---------------- residual + layernorm, all-bf16 stream (f32 math) — R8 variant ----------------
__global__ __launch_bounds__(256) void k_lnres3(u16* curb, const u16* delta,
                                                const void* g, long long gOff,
                                                const void* bb, long long bOff,
                                                const int* flag) {
  int isbf = *flag;
  long long row = blockIdx.x;
  u16* xr = curb + row * Dc;
  const u16* dr = delta + row * Dc;
  int t = threadIdx.x;
  float v[3];
  float s = 0.f;
#pragma unroll
  for (int i = 0; i < 3; ++i) { int c = t + i * 256; v[i] = bf2f(xr[c]) + bf2f(dr[c]); s += v[i]; }
  __shared__ float r1[4], r2[4];
  for (int o = 32; o; o >>= 1) s += __shfl_xor(s, o);
  if ((t & 63) == 0) r1[t >> 6] = s;
  __syncthreads();
  float mean = (r1[0] + r1[1] + r1[2] + r1[3]) * (1.0f / 768.0f);
  float s2 = 0.f;
#pragma unroll
  for (int i = 0; i < 3; ++i) { float d = v[i] - mean; s2 += d * d; }
  for (int o = 32; o; o >>= 1) s2 += __shfl_xor(s2, o);
  if ((t & 63) == 0) r2[t >> 6] = s2;
  __syncthreads();
  float var = (r2[0] + r2[1] + r2[2] + r2[3]) * (1.0f / 768.0f);
  float rstd = rsqrtf(var + 1e-6f);
#pragma unroll
  for (int i = 0; i < 3; ++i) {
    int c = t + i * 256;
    float o = ldf(g, gOff + c, isbf) * (v[i] - mean) * rstd + ldf(bb, bOff + c, isbf);
    xr[c] = f2bf(o);
  }
}

// ---------------- fused flash attention ----------------
template<int DEC>
__global__ __launch_bounds__(256) void k_attn(const u16* __restrict__ Q,
                                              const u16* __restrict__ Kb,
                                              const u16* __restrict__ Vt,
                                              u16* __restrict__ Out,
                                              int Lq, int Lk) {
  __shared__ __align__(16) u16 Kl[64 * 64];
  __shared__ __align__(16) u16 Vl[64 * 64];
  __shared__ __align__(16) u16 Pl[4][16][72];
  const int tid = threadIdx.x, wid = tid >> 6, lane = tid & 63;
  const int qt = blockIdx.x, h = blockIdx.y, b = blockIdx.z;
  const int q0 = qt * 64 + wid * 16;
  const int rl = lane & 15, sx = lane >> 4;
  const int srow = lane >> 3;
  const int scol8 = ((lane & 7) ^ srow) << 3;

  s16x8 qa[2];
  {
    const u16* qrow = Q + ((long long)b * Lq + q0 + rl) * Dc + h * 64;
    qa[0] = *(const s16x8*)(qrow + sx * 8);
    qa[1] = *(const s16x8*)(qrow + 32 + sx * 8);
  }
  f32x4 o[4] = {};
  float m[4], l[4];
#pragma unroll
  for (int e = 0; e < 4; ++e) { m[e] = -3.0e38f; l[e] = 0.f; }

  const long long kbase = (long long)b * Lk * Dc + h * 64;
  const long long vbase = ((long long)b * Dc + h * 64) * Lk;

  for (int k0 = 0; k0 < Lk; k0 += 64) {
#pragma unroll
    for (int g = 0; g < 2; ++g) {
      int chunk = g * 4 + wid;
      gload16(Kb + kbase + (long long)(k0 + chunk * 8 + srow) * Dc + scol8,
              (char*)Kl + chunk * 1024);
    }
#pragma unroll
    for (int g = 0; g < 2; ++g) {
      int chunk = g * 4 + wid;
      gload16(Vt + vbase + (long long)(chunk * 8 + srow) * Lk + k0 + scol8,
              (char*)Vl + chunk * 1024);
    }
    asm volatile("s_waitcnt vmcnt(0)" ::: "memory");
    barx();

    f32x4 s[4];
#pragma unroll
    for (int n = 0; n < 4; ++n) {
      s16x8 b0 = *(const s16x8*)((char*)Kl + (n * 16 + rl) * 128 + ((sx    ) ^ (rl & 7)) * 16);
      s16x8 b1 = *(const s16x8*)((char*)Kl + (n * 16 + rl) * 128 + ((sx + 4) ^ (rl & 7)) * 16);
      f32x4 acc = {};
      acc = __builtin_amdgcn_mfma_f32_16x16x32_bf16(qa[0], b0, acc, 0, 0, 0);
      acc = __builtin_amdgcn_mfma_f32_16x16x32_bf16(qa[1], b1, acc, 0, 0, 0);
      s[n] = acc;
    }
#pragma unroll
    for (int n = 0; n < 4; ++n)
#pragma unroll
      for (int e = 0; e < 4; ++e) s[n][e] *= 0.125f;

#pragma unroll
    for (int e = 0; e < 4; ++e) {
      float v = fmaxf(fmaxf(s[0][e], s[1][e]), fmaxf(s[2][e], s[3][e]));
      v = fmaxf(v, __shfl_xor(v, 1));
      v = fmaxf(v, __shfl_xor(v, 2));
      v = fmaxf(v, __shfl_xor(v, 4));
      v = fmaxf(v, __shfl_xor(v, 8));
      float mn = fmaxf(m[e], v);
      float alpha = __expf(m[e] - mn);
      m[e] = mn;
      float ls = 0.f;
#pragma unroll
      for (int n = 0; n < 4; ++n) {
        float p = __expf(s[n][e] - mn);
        s[n][e] = p;
        ls += p;
      }
      ls += __shfl_xor(ls, 1);
      ls += __shfl_xor(ls, 2);
      ls += __shfl_xor(ls, 4);
      ls += __shfl_xor(ls, 8);
      l[e] = l[e] * alpha + ls;
#pragma unroll
      for (int n = 0; n < 4; ++n) o[n][e] *= alpha;
    }

#pragma unroll
    for (int e = 0; e < 4; ++e)
#pragma unroll
      for (int n = 0; n < 4; ++n)
        Pl[wid][sx * 4 + e][n * 16 + rl] = f2bf(s[n][e]);
    barx();

    s16x8 pa0 = *(const s16x8*)&Pl[wid][rl][sx * 8];
    s16x8 pa1 = *(const s16x8*)&Pl[wid][rl][32 + sx * 8];
#pragma unroll
    for (int n = 0; n < 4; ++n) {
      s16x8 v0 = *(const s16x8*)((char*)Vl + (n * 16 + rl) * 128 + ((sx    ) ^ (rl & 7)) * 16);
      s16x8 v1 = *(const s16x8*)((char*)Vl + (n * 16 + rl) * 128 + ((sx + 4) ^ (rl & 7)) * 16);
      o[n] = __builtin_amdgcn_mfma_f32_16x16x32_bf16(pa0, v0, o[n], 0, 0, 0);
      o[n] = __builtin_amdgcn_mfma_f32_16x16x32_bf16(pa1, v1, o[n], 0, 0, 0);
    }
    barx();
  }

#pragma unroll
  for (int e = 0; e < 4; ++e) l[e] = 1.0f / l[e];
  if (DEC) {
    u16* Op = Out + ((long long)b * Dc + h * 64) * LXc;
#pragma unroll
    for (int n = 0; n < 4; ++n) {
      union { u16 u[4]; uint2 d; } pk;
#pragma unroll
      for (int e = 0; e < 4; ++e) pk.u[e] = f2bf(o[n][e] * l[e]);
      *(uint2*)&Op[(long long)(n * 16 + rl) * LXc + q0 + sx * 4] = pk.d;
    }
  } else {
    u16* Op = Out + ((long long)b * Lq + q0) * Dc + h * 64;
#pragma unroll
    for (int n = 0; n < 4; ++n)
#pragma unroll
      for (int e = 0; e < 4; ++e)
        Op[(long long)(sx * 4 + e) * Dc + n * 16 + rl] = f2bf(o[n][e] * l[e]);
  }
}

// ---------------- GEMM param block ----------------
struct G2 {
  const u16* A; long long lda, sAb, sAh;
  const u16* W; long long ldw, sWb, sWh;
  const float* bias; long long bOff;
  void* C; long long ldc, sCb, sCh;
  void* Ck; void* Cv; int vSeg;
  int Hdim; float scale; int relu; int Lseq;
};

// ---------------- BMxBN 2-phase MFMA GEMM with T2 LDS swizzle (R8 structure, best measured) ----
template<int BM, int BN, int MODE>
__global__ __launch_bounds__(256, 2) void gemm2(G2 p, int M, int N, int K) {
  constexpr int BK = 64;
  __shared__ __align__(16) u16 Al[BM * BK];
  __shared__ __align__(16) u16 Bl[BN * BK];
  const int tid = threadIdx.x, wid = tid >> 6, lane = tid & 63;
  const int z = blockIdx.z, zb = z / p.Hdim, zh = z % p.Hdim;
  int bx = blockIdx.x, by = blockIdx.y;
  if (gridDim.z == 1) {
    int gx = gridDim.x, nwg = gx * gridDim.y;
    int orig = by * gx + bx;
    int q = nwg >> 3, r = nwg & 7, xcd = orig & 7, lin = orig >> 3;
    int wg = (xcd < r ? xcd * (q + 1) : r * (q + 1) + (xcd - r) * q) + lin;
    bx = wg % gx; by = wg / gx;
  }
  const u16* A = p.A + (long long)zb * p.sAb + (long long)zh * p.sAh;
  const u16* W = p.W + (long long)zb * p.sWb + (long long)zh * p.sWh;
  const int m0 = by * BM, n0 = bx * BN;
  const int wr = wid >> 1, wc = wid & 1;
  constexpr int FM = BM / 32, FN = BN / 32;
  f32x4 acc[FM][FN] = {};
  const int lr = lane >> 3;
  const int lo = (((lane & 7) ^ lr) << 3) * 2;
  const int rl = lane & 15;
  const int sx = lane >> 4;
  const int slotb0 = (((sx + 0) ^ (rl & 7)) << 4);
  const int slotb1 = (((sx + 4) ^ (rl & 7)) << 4);

  for (int k0 = 0; k0 < K; k0 += BK) {
#pragma unroll
    for (int i = 0; i < FM; ++i) {
      int chunk = wid * FM + i;
      int row = chunk * 8 + lr;
      gload16((const char*)(A + (long long)(m0 + row) * p.lda + k0) + lo,
              (char*)Al + chunk * 1024);
    }
#pragma unroll
    for (int i = 0; i < FN; ++i) {
      int chunk = wid * FN + i;
      int row = chunk * 8 + lr;
      gload16((const char*)(W + (long long)(n0 + row) * p.ldw + k0) + lo,
              (char*)Bl + chunk * 1024);
    }
    __syncthreads();
    {
      s16x8 af[FM][2], bfr[FN][2];
#pragma unroll
      for (int i = 0; i < FM; ++i) {
        const char* rbase = (char*)Al + (wr * (BM / 2) + i * 16 + rl) * 128;
        af[i][0] = *(const s16x8*)(rbase + slotb0);
        af[i][1] = *(const s16x8*)(rbase + slotb1);
      }
#pragma unroll
      for (int j = 0; j < FN; ++j) {
        const char* rbase = (char*)Bl + (wc * (BN / 2) + j * 16 + rl) * 128;
        bfr[j][0] = *(const s16x8*)(rbase + slotb0);
        bfr[j][1] = *(const s16x8*)(rbase + slotb1);
      }
#pragma unroll
      for (int ks = 0; ks < 2; ++ks)
#pragma unroll
        for (int i = 0; i < FM; ++i)
#pragma unroll
          for (int j = 0; j < FN; ++j)
            acc[i][j] = __builtin_amdgcn_mfma_f32_16x16x32_bf16(af[i][ks], bfr[j][ks], acc[i][j], 0, 0, 0);
    }
    __syncthreads();
  }

  const int seg = (MODE == 4) ? (n0 / 768) : 0;
#pragma unroll
  for (int j = 0; j < FN; ++j) {
    int col = n0 + wc * (BN / 2) + j * 16 + (lane & 15);
    float bv = p.bias ? p.bias[p.bOff + col] : 0.f;
#pragma unroll
    for (int i = 0; i < FM; ++i) {
      int row0 = m0 + wr * (BM / 2) + i * 16 + (lane >> 4) * 4;
      if (MODE == 0) {
        u16* C = (u16*)p.C + (long long)zb * p.sCb + (long long)zh * p.sCh;
#pragma unroll
        for (int e = 0; e < 4; ++e) {
          float v = acc[i][j][e] * p.scale + bv;
          if (p.relu) v = fmaxf(v, 0.f);
          C[(long long)(row0 + e) * p.ldc + col] = f2bf(v);
        }
      } else {  // MODE 4: segment-routed QKV
        u16* outp = seg == 0 ? (u16*)p.C : (seg == 1 ? (u16*)p.Ck : (u16*)p.Cv);
        int c = col - seg * 768;
        if (seg == p.vSeg) {
          int b = row0 / p.Lseq, l = row0 % p.Lseq;
          union { u16 u[4]; uint2 d; } pk;
#pragma unroll
          for (int e = 0; e < 4; ++e) pk.u[e] = f2bf(acc[i][j][e] + bv);
          *(uint2*)&outp[((long long)b * Dc + c) * p.Lseq + l] = pk.d;
        } else {
#pragma unroll
          for (int e = 0; e < 4; ++e)
            outp[(long long)(row0 + e) * 768 + c] = f2bf(acc[i][j][e] + bv);
        }
      }
    }
  }
}

// ---------------- launch helpers ----------------
template<int BM, int BN, int MODE>
static void run_gemm(const G2& p, int M, int N, int K, int nz, hipStream_t st) {
  dim3 grid(N / BN, M / BM, nz);
  gemm2<BM, BN, MODE><<<grid, 256, 0, st>>>(p, M, N, K);
}

extern "C" void kernel_launch(void* const* d_in, const int* in_sizes, int n_in,
                              void* d_out, int out_size, void* d_ws, size_t ws_size,
                              hipStream_t stream) {
  const void* y_in  = d_in[0];
  const void* x_in  = d_in[1];
  const void* bbox  = d_in[5];
  const void* enc_aw = d_in[6];  const void* enc_ab = d_in[7];
  const void* enc_w1 = d_in[8];  const void* enc_b1 = d_in[9];
  const void* enc_w2 = d_in[10]; const void* enc_b2 = d_in[11];
  const void* enc_lg = d_in[12]; const void* enc_lb = d_in[13];
  const void* dec_aw = d_in[14]; const void* dec_ab = d_in[15];
  const void* dec_w1 = d_in[16]; const void* dec_b1 = d_in[17];
  const void* dec_w2 = d_in[18]; const void* dec_b2 = d_in[19];
  const void* dec_lg = d_in[20]; const void* dec_lb = d_in[21];

  char* base = (char*)d_ws;
  size_t off = 0;
  auto alloc = [&](size_t bytes) { void* p = base + off; off = (off + bytes + 255) & ~(size_t)255; return p; };
  int*  flag = (int*)alloc(256);
  const long long DD = (long long)Dc * Dc;
  const long long DF = (long long)Dc * FFc;
  u16* WencA  = (u16*)alloc(24 * DD * 2);
  u16* WencW1 = (u16*)alloc(6 * DF * 2);
  u16* WencW2 = (u16*)alloc(6 * DF * 2);
  u16* WdecA  = (u16*)alloc(48 * DD * 2);
  u16* WdecW1 = (u16*)alloc(6 * DF * 2);
  u16* WdecW2 = (u16*)alloc(6 * DF * 2);
  float* BencA  = (float*)alloc(24 * Dc * 4);
  float* BencW1 = (float*)alloc(6 * FFc * 4);
  float* BencW2 = (float*)alloc(6 * Dc * 4);
  float* BdecA  = (float*)alloc(48 * Dc * 4);
  float* BdecW1 = (float*)alloc(6 * FFc * 4);
  float* BdecW2 = (float*)alloc(6 * Dc * 4);
  const long long NYt = (long long)NB * LYc * Dc;
  const long long NXt = (long long)NB * LXc * Dc;
  u16*   curb_y = (u16*)alloc(NYt * 2);
  u16*   curb_x = (u16*)alloc(NXt * 2);
  u16*   simb   = (u16*)alloc((long long)NB * LXc * LXc * 2);
  u16*   qbf    = (u16*)alloc(NXt * 2);
  u16*   kbf    = (u16*)alloc(NXt * 2);
  u16*   vT     = (u16*)alloc(NXt * 2);
  u16*   deltab = (u16*)alloc(NXt * 2);
  u16*   aoT    = (u16*)alloc(NXt * 2);
  u16*   ao2    = (u16*)alloc(NXt * 2);
  u16*   ffmid  = (u16*)alloc((long long)NB * LXc * FFc * 2);

  k_detect<<<1, 64, 0, stream>>>((const u16*)y_in, flag);
  k_ingest_b4<<<1024, 256, 0, stream>>>(y_in, curb_y, NYt / 4, flag);
  k_ingest_b4<<<1024, 256, 0, stream>>>(x_in, curb_x, NXt / 4, flag);
  k_bboxsim<<<NB * LXc, 256, 0, stream>>>(bbox, flag, simb);
  k_wt2<<<dim3(Dc/64, Dc/64, 24), 256, 0, stream>>>(enc_aw, WencA, Dc, Dc, flag);
  k_wt2<<<dim3(FFc/64, Dc/64, 6), 256, 0, stream>>>(enc_w1, WencW1, Dc, FFc, flag);
  k_wt2<<<dim3(Dc/64, FFc/64, 6), 256, 0, stream>>>(enc_w2, WencW2, FFc, Dc, flag);
  k_wt2<<<dim3(Dc/64, Dc/64, 48), 256, 0, stream>>>(dec_aw, WdecA, Dc, Dc, flag);
  k_wt2<<<dim3(FFc/64, Dc/64, 6), 256, 0, stream>>>(dec_w1, WdecW1, Dc, FFc, flag);
  k_wt2<<<dim3(Dc/64, FFc/64, 6), 256, 0, stream>>>(dec_w2, WdecW2, FFc, Dc, flag);
  k_cvt<<<32, 256, 0, stream>>>(enc_ab, BencA, 24 * Dc, flag);
  k_cvt<<<32, 256, 0, stream>>>(enc_b1, BencW1, 6 * FFc, flag);
  k_cvt<<<32, 256, 0, stream>>>(enc_b2, BencW2, 6 * Dc, flag);
  k_cvt<<<32, 256, 0, stream>>>(dec_ab, BdecA, 48 * Dc, flag);
  k_cvt<<<32, 256, 0, stream>>>(dec_b1, BdecW1, 6 * FFc, flag);
  k_cvt<<<32, 256, 0, stream>>>(dec_b2, BdecW2, 6 * Dc, flag);

  // ---- helpers (R8 routing: best measured) ----
  auto qkv = [&](const u16* A, int M, const u16* Wt, long long wOff,
                 const float* bias, long long bOff, int Lseq) {
    G2 p{}; p.A = A; p.lda = Dc; p.W = Wt + wOff; p.ldw = Dc;
    p.bias = bias; p.bOff = bOff;
    p.C = qbf; p.Ck = kbf; p.Cv = vT; p.vSeg = 2;
    p.Hdim = 1; p.scale = 1.f; p.Lseq = Lseq;
    run_gemm<128, 128, 4>(p, M, 3 * Dc, Dc, 1, stream);
  };
  auto kv = [&](const u16* A, int M, const u16* Wt, long long wOff,
                const float* bias, long long bOff, int Lseq) {
    G2 p{}; p.A = A; p.lda = Dc; p.W = Wt + wOff; p.ldw = Dc;
    p.bias = bias; p.bOff = bOff;
    p.C = kbf; p.Ck = vT; p.vSeg = 1;
    p.Hdim = 1; p.scale = 1.f; p.Lseq = Lseq;
    run_gemm<128, 128, 4>(p, M, 2 * Dc, Dc, 1, stream);
  };
  auto p768 = [&](const u16* A, int M, const u16* Wt, long long wOff,
                  const float* bias, long long bOff, u16* C, int K, int relu) {
    G2 p{}; p.A = A; p.lda = K; p.W = Wt + wOff; p.ldw = K;
    p.bias = bias; p.bOff = bOff; p.C = C; p.ldc = Dc;
    p.Hdim = 1; p.scale = 1.f; p.relu = relu;
    run_gemm<128, 64, 0>(p, M, Dc, K, 1, stream);
  };
  auto ffn1 = [&](const u16* A, int M, const u16* Wt, long long wOff,
                  const float* bias, long long bOff) {
    G2 p{}; p.A = A; p.lda = Dc; p.W = Wt + wOff; p.ldw = Dc;
    p.bias = bias; p.bOff = bOff; p.C = ffmid; p.ldc = FFc;
    p.Hdim = 1; p.scale = 1.f; p.relu = 1;
    run_gemm<128, 128, 0>(p, M, FFc, Dc, 1, stream);
  };
  auto g_rel = [&]() {
    G2 p{}; p.A = simb; p.lda = LXc; p.sAb = (long long)LXc * LXc;
    p.W = aoT; p.ldw = LXc; p.sWb = (long long)Dc * LXc;
    p.C = ao2; p.ldc = Dc; p.sCb = (long long)LXc * Dc;
    p.Hdim = 1; p.scale = 1.f;
    run_gemm<128, 128, 0>(p, LXc, Dc, LXc, NB, stream);
  };

  // ---- encoder (M = 4096) ----
  for (int i = 0; i < 6; ++i) {
    int M = NB * LYc;
    long long wo = (long long)i * 4 * DD, bo = (long long)i * 4 * Dc;
    qkv(curb_y, M, WencA, wo, BencA, bo, LYc);
    k_attn<0><<<dim3(LYc / 64, NH, NB), 256, 0, stream>>>(qbf, kbf, vT, ao2, LYc, LYc);
    p768(ao2, M, WencA, wo + 3 * DD, BencA, bo + 3 * Dc, deltab, Dc, 0);
    k_lnres3<<<M, 256, 0, stream>>>(curb_y, deltab, enc_lg, (long long)(i*2+0)*Dc, enc_lb, (long long)(i*2+0)*Dc, flag);
    ffn1(curb_y, M, WencW1, (long long)i * DF, BencW1, (long long)i * FFc);
    p768(ffmid, M, WencW2, (long long)i * DF, BencW2, (long long)i * Dc, deltab, FFc, 0);
    k_lnres3<<<M, 256, 0, stream>>>(curb_y, deltab, enc_lg, (long long)(i*2+1)*Dc, enc_lb, (long long)(i*2+1)*Dc, flag);
  }

  // ---- decoder (M = 8192) ----
  for (int i = 0; i < 6; ++i) {
    int M = NB * LXc;
    for (int a = 0; a < 2; ++a) {
      long long wo = (long long)(i * 2 + a) * 4 * DD;
      long long bo = (long long)(i * 2 + a) * 4 * Dc;
      int Lk;
      if (a == 0) {
        qkv(curb_x, M, WdecA, wo, BdecA, bo, LXc);
        Lk = LXc;
      } else {
        p768(curb_x, M, WdecA, wo, BdecA, bo, qbf, Dc, 0);
        kv(curb_y, NB * LYc, WdecA, wo + DD, BdecA, bo + Dc, LYc);
        Lk = LYc;
      }
      k_attn<1><<<dim3(LXc / 64, NH, NB), 256, 0, stream>>>(qbf, kbf, vT, aoT, LXc, Lk);
      g_rel();
      p768(ao2, M, WdecA, wo + 3 * DD, BdecA, bo + 3 * Dc, deltab, Dc, 0);
      k_lnres3<<<M, 256, 0, stream>>>(curb_x, deltab, dec_lg, (long long)(i*3+a)*Dc, dec_lb, (long long)(i*3+a)*Dc, flag);
    }
    ffn1(curb_x, M, WdecW1, (long long)i * DF, BdecW1, (long long)i * FFc);
    p768(ffmid, M, WdecW2, (long long)i * DF, BdecW2, (long long)i * Dc, deltab, FFc, 0);
    k_lnres3<<<M, 256, 0, stream>>>(curb_x, deltab, dec_lg, (long long)(i*3+2)*Dc, dec_lb, (long long)(i*3+2)*Dc, flag);
  }

  k_emit4<<<2048, 256, 0, stream>>>(curb_y, curb_x, d_out, flag, NYt / 4, (NYt + NXt) / 4);
}

// Round 13
// 3106.112 us; speedup vs baseline: 1.1063x; 1.0022x over previous
//
#include <hip/hip_runtime.h>

#define DEV __device__ __forceinline__

constexpr int NB  = 32;
constexpr int LXc = 256;
constexpr int LYc = 128;
constexpr int Dc  = 768;
constexpr int NH  = 12;
constexpr int FFc = 3072;

typedef unsigned short u16;
typedef float f32x4 __attribute__((ext_vector_type(4)));
typedef short s16x8 __attribute__((ext_vector_type(8)));

DEV u16 f2bf(float f) {
  unsigned u = __float_as_uint(f);
  u += 0x7FFFu + ((u >> 16) & 1u);
  return (u16)(u >> 16);
}
DEV float bf2f(u16 w) { return __uint_as_float(((unsigned)w) << 16); }
DEV float ldf(const void* p, long long i, int isbf) {
  return isbf ? bf2f(((const u16*)p)[i]) : ((const float*)p)[i];
}

DEV void gload16(const void* g, void* l) {
  __builtin_amdgcn_global_load_lds(
      (const __attribute__((address_space(1))) void*)g,
      (__attribute__((address_space(3))) void*)l, 16, 0, 0);
}
DEV void barx() {
  asm volatile("" ::: "memory");
  __builtin_amdgcn_s_barrier();
  asm volatile("" ::: "memory");
}

// ---------------- dtype detection ----------------
__global__ void k_detect(const u16* y, int* flag) {
  if (threadIdx.x == 0) {
    int cnt = 0;
    for (int i = 0; i < 256; ++i) {
      u16 w = y[i];
      int e = (w >> 7) & 0xFF;
      if (e == 0 || (e >= 112 && e <= 140)) cnt++;
    }
    *flag = (cnt >= 200) ? 1 : 0;
  }
}

// raw -> bf16 stream, vectorized 4 elems/lane
__global__ void k_ingest_b4(const void* src, u16* dst, long long n4, const int* flag) {
  int isbf = *flag;
  long long i = (long long)blockIdx.x * blockDim.x + threadIdx.x;
  long long st = (long long)gridDim.x * blockDim.x;
  for (; i < n4; i += st) {
    union { u16 u[4]; uint2 d; } v;
    if (isbf) v.d = ((const uint2*)src)[i];
    else {
      float4 f = ((const float4*)src)[i];
      v.u[0] = f2bf(f.x); v.u[1] = f2bf(f.y); v.u[2] = f2bf(f.z); v.u[3] = f2bf(f.w);
    }
    ((uint2*)dst)[i] = v.d;
  }
}

__global__ void k_cvt(const void* src, float* dst, long long n, const int* flag) {
  int isbf = *flag;
  long long i = (long long)blockIdx.x * blockDim.x + threadIdx.x;
  long long st = (long long)gridDim.x * blockDim.x;
  for (; i < n; i += st) dst[i] = ldf(src, i, isbf);
}

// ---------------- vectorized weight transpose+convert: [R][C] raw -> [C][R] bf16 ----------------
__global__ __launch_bounds__(256) void k_wt2(const void* src, u16* dst, int R, int C, const int* flag) {
  int isbf = *flag;
  __shared__ u16 t[64][72];
  long long base = (long long)blockIdx.z * R * C;
  int c0 = blockIdx.x * 64, r0 = blockIdx.y * 64;
  int tr = threadIdx.x >> 4;
  int tc4 = (threadIdx.x & 15) * 4;
#pragma unroll
  for (int k = 0; k < 4; ++k) {
    int r = tr + k * 16;
    union { u16 u[4]; uint2 d; } v;
    if (isbf) {
      v.d = *(const uint2*)((const u16*)src + base + (long long)(r0 + r) * C + c0 + tc4);
    } else {
      float4 f = *(const float4*)((const float*)src + base + (long long)(r0 + r) * C + c0 + tc4);
      v.u[0] = f2bf(f.x); v.u[1] = f2bf(f.y); v.u[2] = f2bf(f.z); v.u[3] = f2bf(f.w);
    }
    *(uint2*)&t[r][tc4] = v.d;
  }
  __syncthreads();
#pragma unroll
  for (int k = 0; k < 4; ++k) {
    int c = tr + k * 16;
    union { u16 u[4]; uint2 d; } v;
#pragma unroll
    for (int j = 0; j < 4; ++j) v.u[j] = t[tc4 + j][c];
    *(uint2*)&dst[base + (long long)(c0 + c) * R + r0 + tc4] = v.d;
  }
}

// ---------------- bbox cosine-sim + softmax (bf16 out) ----------------
__global__ __launch_bounds__(256) void k_bboxsim(const void* bbox, const int* flag, u16* sim) {
  int isbf = *flag;
  int b = blockIdx.x >> 8, i = blockIdx.x & 255;
  int j = threadIdx.x;
  long long base = (long long)b * LXc * 4;
  float a[4], c[4];
#pragma unroll
  for (int t = 0; t < 4; ++t) {
    a[t] = ldf(bbox, base + (long long)i * 4 + t, isbf);
    c[t] = ldf(bbox, base + (long long)j * 4 + t, isbf);
  }
  float dot = a[0]*c[0] + a[1]*c[1] + a[2]*c[2] + a[3]*c[3];
  float na  = sqrtf(a[0]*a[0] + a[1]*a[1] + a[2]*a[2] + a[3]*a[3]);
  float ncn = sqrtf(c[0]*c[0] + c[1]*c[1] + c[2]*c[2] + c[3]*c[3]);
  float v = dot / (na * ncn);
  __shared__ float r1[4], r2[4];
  float m = v;
  for (int o = 32; o; o >>= 1) m = fmaxf(m, __shfl_xor(m, o));
  if ((threadIdx.x & 63) == 0) r1[threadIdx.x >> 6] = m;
  __syncthreads();
  m = fmaxf(fmaxf(r1[0], r1[1]), fmaxf(r1[2], r1[3]));
  float e = __expf(v - m);
  float s = e;
  for (int o = 32; o; o >>= 1) s += __shfl_xor(s, o);
  if ((threadIdx.x & 63) == 0) r2[threadIdx.x >> 6] = s;
  __syncthreads();
  s = r2[0] + r2[1] + r2[2] + r2[3];
  sim[((long long)b * LXc + i) * LXc + j] = f2bf(e / s);
}

// ---------------- residual + layernorm, bf16 stream; EMIT=1 also writes d_out ----------------
template<int EMIT>
__global__ __launch_bounds__(256) void k_lnres3(u16* curb, const u16* delta,
                                                const void* g, long long gOff,
                                                const void* bb, long long bOff,
                                                const int* flag,
                                                void* out, long long oBase) {
  int isbf = *flag;
  long long row = blockIdx.x;
  u16* xr = curb + row * Dc;
  const u16* dr = delta + row * Dc;
  int t = threadIdx.x;
  float v[3];
  float s = 0.f;
#pragma unroll
  for (int i = 0; i < 3; ++i) { int c = t + i * 256; v[i] = bf2f(xr[c]) + bf2f(dr[c]); s += v[i]; }
  __shared__ float r1[4], r2[4];
  for (int o = 32; o; o >>= 1) s += __shfl_xor(s, o);
  if ((t & 63) == 0) r1[t >> 6] = s;
  __syncthreads();
  float mean = (r1[0] + r1[1] + r1[2] + r1[3]) * (1.0f / 768.0f);
  float s2 = 0.f;
#pragma unroll
  for (int i = 0; i < 3; ++i) { float d = v[i] - mean; s2 += d * d; }
  for (int o = 32; o; o >>= 1) s2 += __shfl_xor(s2, o);
  if ((t & 63) == 0) r2[t >> 6] = s2;
  __syncthreads();
  float var = (r2[0] + r2[1] + r2[2] + r2[3]) * (1.0f / 768.0f);
  float rstd = rsqrtf(var + 1e-6f);
#pragma unroll
  for (int i = 0; i < 3; ++i) {
    int c = t + i * 256;
    float o = ldf(g, gOff + c, isbf) * (v[i] - mean) * rstd + ldf(bb, bOff + c, isbf);
    u16 ob = f2bf(o);
    xr[c] = ob;
    if (EMIT) {
      long long oi = oBase + row * Dc + c;
      if (isbf) ((u16*)out)[oi] = ob;
      else      ((float*)out)[oi] = bf2f(ob);
    }
  }
}

// ---------------- fused flash attention ----------------
template<int DEC>
__global__ __launch_bounds__(256) void k_attn(const u16* __restrict__ Q,
                                              const u16* __restrict__ Kb,
                                              const u16* __restrict__ Vt,
                                              u16* __restrict__ Out,
                                              int Lq, int Lk) {
  __shared__ __align__(16) u16 Kl[64 * 64];
  __shared__ __align__(16) u16 Vl[64 * 64];
  __shared__ __align__(16) u16 Pl[4][16][72];
  const int tid = threadIdx.x, wid = tid >> 6, lane = tid & 63;
  const int qt = blockIdx.x, h = blockIdx.y, b = blockIdx.z;
  const int q0 = qt * 64 + wid * 16;
  const int rl = lane & 15, sx = lane >> 4;
  const int srow = lane >> 3;
  const int scol8 = ((lane & 7) ^ srow) << 3;

  s16x8 qa[2];
  {
    const u16* qrow = Q + ((long long)b * Lq + q0 + rl) * Dc + h * 64;
    qa[0] = *(const s16x8*)(qrow + sx * 8);
    qa[1] = *(const s16x8*)(qrow + 32 + sx * 8);
  }
  f32x4 o[4] = {};
  float m[4], l[4];
#pragma unroll
  for (int e = 0; e < 4; ++e) { m[e] = -3.0e38f; l[e] = 0.f; }

  const long long kbase = (long long)b * Lk * Dc + h * 64;
  const long long vbase = ((long long)b * Dc + h * 64) * Lk;

  for (int k0 = 0; k0 < Lk; k0 += 64) {
#pragma unroll
    for (int g = 0; g < 2; ++g) {
      int chunk = g * 4 + wid;
      gload16(Kb + kbase + (long long)(k0 + chunk * 8 + srow) * Dc + scol8,
              (char*)Kl + chunk * 1024);
    }
#pragma unroll
    for (int g = 0; g < 2; ++g) {
      int chunk = g * 4 + wid;
      gload16(Vt + vbase + (long long)(chunk * 8 + srow) * Lk + k0 + scol8,
              (char*)Vl + chunk * 1024);
    }
    asm volatile("s_waitcnt vmcnt(0)" ::: "memory");
    barx();

    f32x4 s[4];
#pragma unroll
    for (int n = 0; n < 4; ++n) {
      s16x8 b0 = *(const s16x8*)((char*)Kl + (n * 16 + rl) * 128 + ((sx    ) ^ (rl & 7)) * 16);
      s16x8 b1 = *(const s16x8*)((char*)Kl + (n * 16 + rl) * 128 + ((sx + 4) ^ (rl & 7)) * 16);
      f32x4 acc = {};
      acc = __builtin_amdgcn_mfma_f32_16x16x32_bf16(qa[0], b0, acc, 0, 0, 0);
      acc = __builtin_amdgcn_mfma_f32_16x16x32_bf16(qa[1], b1, acc, 0, 0, 0);
      s[n] = acc;
    }
#pragma unroll
    for (int n = 0; n < 4; ++n)
#pragma unroll
      for (int e = 0; e < 4; ++e) s[n][e] *= 0.125f;

#pragma unroll
    for (int e = 0; e < 4; ++e) {
      float v = fmaxf(fmaxf(s[0][e], s[1][e]), fmaxf(s[2][e], s[3][e]));
      v = fmaxf(v, __shfl_xor(v, 1));
      v = fmaxf(v, __shfl_xor(v, 2));
      v = fmaxf(v, __shfl_xor(v, 4));
      v = fmaxf(v, __shfl_xor(v, 8));
      float mn = fmaxf(m[e], v);
      float alpha = __expf(m[e] - mn);
      m[e] = mn;
      float ls = 0.f;
#pragma unroll
      for (int n = 0; n < 4; ++n) {
        float p = __expf(s[n][e] - mn);
        s[n][e] = p;
        ls += p;
      }
      ls += __shfl_xor(ls, 1);
      ls += __shfl_xor(ls, 2);
      ls += __shfl_xor(ls, 4);
      ls += __shfl_xor(ls, 8);
      l[e] = l[e] * alpha + ls;
#pragma unroll
      for (int n = 0; n < 4; ++n) o[n][e] *= alpha;
    }

#pragma unroll
    for (int e = 0; e < 4; ++e)
#pragma unroll
      for (int n = 0; n < 4; ++n)
        Pl[wid][sx * 4 + e][n * 16 + rl] = f2bf(s[n][e]);
    barx();

    s16x8 pa0 = *(const s16x8*)&Pl[wid][rl][sx * 8];
    s16x8 pa1 = *(const s16x8*)&Pl[wid][rl][32 + sx * 8];
#pragma unroll
    for (int n = 0; n < 4; ++n) {
      s16x8 v0 = *(const s16x8*)((char*)Vl + (n * 16 + rl) * 128 + ((sx    ) ^ (rl & 7)) * 16);
      s16x8 v1 = *(const s16x8*)((char*)Vl + (n * 16 + rl) * 128 + ((sx + 4) ^ (rl & 7)) * 16);
      o[n] = __builtin_amdgcn_mfma_f32_16x16x32_bf16(pa0, v0, o[n], 0, 0, 0);
      o[n] = __builtin_amdgcn_mfma_f32_16x16x32_bf16(pa1, v1, o[n], 0, 0, 0);
    }
    barx();
  }

#pragma unroll
  for (int e = 0; e < 4; ++e) l[e] = 1.0f / l[e];
  if (DEC) {
    u16* Op = Out + ((long long)b * Dc + h * 64) * LXc;
#pragma unroll
    for (int n = 0; n < 4; ++n) {
      union { u16 u[4]; uint2 d; } pk;
#pragma unroll
      for (int e = 0; e < 4; ++e) pk.u[e] = f2bf(o[n][e] * l[e]);
      *(uint2*)&Op[(long long)(n * 16 + rl) * LXc + q0 + sx * 4] = pk.d;
    }
  } else {
    u16* Op = Out + ((long long)b * Lq + q0) * Dc + h * 64;
#pragma unroll
    for (int n = 0; n < 4; ++n)
#pragma unroll
      for (int e = 0; e < 4; ++e)
        Op[(long long)(sx * 4 + e) * Dc + n * 16 + rl] = f2bf(o[n][e] * l[e]);
  }
}

// ---------------- GEMM param block ----------------
struct G2 {
  const u16* A; long long lda, sAb, sAh;
  const u16* W; long long ldw, sWb, sWh;
  const float* bias; long long bOff;
  void* C; long long ldc, sCb, sCh;
  void* Ck; void* Cv; int vSeg;
  int Hdim; float scale; int relu; int Lseq;
};

// ---------------- BMxBN 2-phase MFMA GEMM with T2 LDS swizzle (best measured) ----------------
template<int BM, int BN, int MODE>
__global__ __launch_bounds__(256, 2) void gemm2(G2 p, int M, int N, int K) {
  constexpr int BK = 64;
  __shared__ __align__(16) u16 Al[BM * BK];
  __shared__ __align__(16) u16 Bl[BN * BK];
  const int tid = threadIdx.x, wid = tid >> 6, lane = tid & 63;
  const int z = blockIdx.z, zb = z / p.Hdim, zh = z % p.Hdim;
  int bx = blockIdx.x, by = blockIdx.y;
  if (gridDim.z == 1) {
    int gx = gridDim.x, nwg = gx * gridDim.y;
    int orig = by * gx + bx;
    int q = nwg >> 3, r = nwg & 7, xcd = orig & 7, lin = orig >> 3;
    int wg = (xcd < r ? xcd * (q + 1) : r * (q + 1) + (xcd - r) * q) + lin;
    bx = wg % gx; by = wg / gx;
  }
  const u16* A = p.A + (long long)zb * p.sAb + (long long)zh * p.sAh;
  const u16* W = p.W + (long long)zb * p.sWb + (long long)zh * p.sWh;
  const int m0 = by * BM, n0 = bx * BN;
  const int wr = wid >> 1, wc = wid & 1;
  constexpr int FM = BM / 32, FN = BN / 32;
  f32x4 acc[FM][FN] = {};
  const int lr = lane >> 3;
  const int lo = (((lane & 7) ^ lr) << 3) * 2;
  const int rl = lane & 15;
  const int sx = lane >> 4;
  const int slotb0 = (((sx + 0) ^ (rl & 7)) << 4);
  const int slotb1 = (((sx + 4) ^ (rl & 7)) << 4);

  for (int k0 = 0; k0 < K; k0 += BK) {
#pragma unroll
    for (int i = 0; i < FM; ++i) {
      int chunk = wid * FM + i;
      int row = chunk * 8 + lr;
      gload16((const char*)(A + (long long)(m0 + row) * p.lda + k0) + lo,
              (char*)Al + chunk * 1024);
    }
#pragma unroll
    for (int i = 0; i < FN; ++i) {
      int chunk = wid * FN + i;
      int row = chunk * 8 + lr;
      gload16((const char*)(W + (long long)(n0 + row) * p.ldw + k0) + lo,
              (char*)Bl + chunk * 1024);
    }
    __syncthreads();
    {
      s16x8 af[FM][2], bfr[FN][2];
#pragma unroll
      for (int i = 0; i < FM; ++i) {
        const char* rbase = (char*)Al + (wr * (BM / 2) + i * 16 + rl) * 128;
        af[i][0] = *(const s16x8*)(rbase + slotb0);
        af[i][1] = *(const s16x8*)(rbase + slotb1);
      }
#pragma unroll
      for (int j = 0; j < FN; ++j) {
        const char* rbase = (char*)Bl + (wc * (BN / 2) + j * 16 + rl) * 128;
        bfr[j][0] = *(const s16x8*)(rbase + slotb0);
        bfr[j][1] = *(const s16x8*)(rbase + slotb1);
      }
#pragma unroll
      for (int ks = 0; ks < 2; ++ks)
#pragma unroll
        for (int i = 0; i < FM; ++i)
#pragma unroll
          for (int j = 0; j < FN; ++j)
            acc[i][j] = __builtin_amdgcn_mfma_f32_16x16x32_bf16(af[i][ks], bfr[j][ks], acc[i][j], 0, 0, 0);
    }
    __syncthreads();
  }

  const int seg = (MODE == 4) ? (n0 / 768) : 0;
#pragma unroll
  for (int j = 0; j < FN; ++j) {
    int col = n0 + wc * (BN / 2) + j * 16 + (lane & 15);
    float bv = p.bias ? p.bias[p.bOff + col] : 0.f;
#pragma unroll
    for (int i = 0; i < FM; ++i) {
      int row0 = m0 + wr * (BM / 2) + i * 16 + (lane >> 4) * 4;
      if (MODE == 0) {
        u16* C = (u16*)p.C + (long long)zb * p.sCb + (long long)zh * p.sCh;
#pragma unroll
        for (int e = 0; e < 4; ++e) {
          float v = acc[i][j][e] * p.scale + bv;
          if (p.relu) v = fmaxf(v, 0.f);
          C[(long long)(row0 + e) * p.ldc + col] = f2bf(v);
        }
      } else {  // MODE 4: segment-routed QKV
        u16* outp = seg == 0 ? (u16*)p.C : (seg == 1 ? (u16*)p.Ck : (u16*)p.Cv);
        int c = col - seg * 768;
        if (seg == p.vSeg) {
          int b = row0 / p.Lseq, l = row0 % p.Lseq;
          union { u16 u[4]; uint2 d; } pk;
#pragma unroll
          for (int e = 0; e < 4; ++e) pk.u[e] = f2bf(acc[i][j][e] + bv);
          *(uint2*)&outp[((long long)b * Dc + c) * p.Lseq + l] = pk.d;
        } else {
#pragma unroll
          for (int e = 0; e < 4; ++e)
            outp[(long long)(row0 + e) * 768 + c] = f2bf(acc[i][j][e] + bv);
        }
      }
    }
  }
}

// ---------------- launch helpers ----------------
template<int BM, int BN, int MODE>
static void run_gemm(const G2& p, int M, int N, int K, int nz, hipStream_t st) {
  dim3 grid(N / BN, M / BM, nz);
  gemm2<BM, BN, MODE><<<grid, 256, 0, st>>>(p, M, N, K);
}

extern "C" void kernel_launch(void* const* d_in, const int* in_sizes, int n_in,
                              void* d_out, int out_size, void* d_ws, size_t ws_size,
                              hipStream_t stream) {
  const void* y_in  = d_in[0];
  const void* x_in  = d_in[1];
  const void* bbox  = d_in[5];
  const void* enc_aw = d_in[6];  const void* enc_ab = d_in[7];
  const void* enc_w1 = d_in[8];  const void* enc_b1 = d_in[9];
  const void* enc_w2 = d_in[10]; const void* enc_b2 = d_in[11];
  const void* enc_lg = d_in[12]; const void* enc_lb = d_in[13];
  const void* dec_aw = d_in[14]; const void* dec_ab = d_in[15];
  const void* dec_w1 = d_in[16]; const void* dec_b1 = d_in[17];
  const void* dec_w2 = d_in[18]; const void* dec_b2 = d_in[19];
  const void* dec_lg = d_in[20]; const void* dec_lb = d_in[21];

  char* base = (char*)d_ws;
  size_t off = 0;
  auto alloc = [&](size_t bytes) { void* p = base + off; off = (off + bytes + 255) & ~(size_t)255; return p; };
  int*  flag = (int*)alloc(256);
  const long long DD = (long long)Dc * Dc;
  const long long DF = (long long)Dc * FFc;
  u16* WencA  = (u16*)alloc(24 * DD * 2);
  u16* WencW1 = (u16*)alloc(6 * DF * 2);
  u16* WencW2 = (u16*)alloc(6 * DF * 2);
  u16* WdecA  = (u16*)alloc(48 * DD * 2);
  u16* WdecW1 = (u16*)alloc(6 * DF * 2);
  u16* WdecW2 = (u16*)alloc(6 * DF * 2);
  float* BencA  = (float*)alloc(24 * Dc * 4);
  float* BencW1 = (float*)alloc(6 * FFc * 4);
  float* BencW2 = (float*)alloc(6 * Dc * 4);
  float* BdecA  = (float*)alloc(48 * Dc * 4);
  float* BdecW1 = (float*)alloc(6 * FFc * 4);
  float* BdecW2 = (float*)alloc(6 * Dc * 4);
  const long long NYt = (long long)NB * LYc * Dc;
  const long long NXt = (long long)NB * LXc * Dc;
  u16*   curb_y = (u16*)alloc(NYt * 2);
  u16*   curb_x = (u16*)alloc(NXt * 2);
  u16*   simb   = (u16*)alloc((long long)NB * LXc * LXc * 2);
  u16*   qbf    = (u16*)alloc(NXt * 2);
  u16*   kbf    = (u16*)alloc(NXt * 2);
  u16*   vT     = (u16*)alloc(NXt * 2);
  u16*   deltab = (u16*)alloc(NXt * 2);
  u16*   aoT    = (u16*)alloc(NXt * 2);
  u16*   ao2    = (u16*)alloc(NXt * 2);
  u16*   ffmid  = (u16*)alloc((long long)NB * LXc * FFc * 2);

  k_detect<<<1, 64, 0, stream>>>((const u16*)y_in, flag);
  k_ingest_b4<<<1024, 256, 0, stream>>>(y_in, curb_y, NYt / 4, flag);
  k_ingest_b4<<<1024, 256, 0, stream>>>(x_in, curb_x, NXt / 4, flag);
  k_bboxsim<<<NB * LXc, 256, 0, stream>>>(bbox, flag, simb);
  k_wt2<<<dim3(Dc/64, Dc/64, 24), 256, 0, stream>>>(enc_aw, WencA, Dc, Dc, flag);
  k_wt2<<<dim3(FFc/64, Dc/64, 6), 256, 0, stream>>>(enc_w1, WencW1, Dc, FFc, flag);
  k_wt2<<<dim3(Dc/64, FFc/64, 6), 256, 0, stream>>>(enc_w2, WencW2, FFc, Dc, flag);
  k_wt2<<<dim3(Dc/64, Dc/64, 48), 256, 0, stream>>>(dec_aw, WdecA, Dc, Dc, flag);
  k_wt2<<<dim3(FFc/64, Dc/64, 6), 256, 0, stream>>>(dec_w1, WdecW1, Dc, FFc, flag);
  k_wt2<<<dim3(Dc/64, FFc/64, 6), 256, 0, stream>>>(dec_w2, WdecW2, FFc, Dc, flag);
  k_cvt<<<32, 256, 0, stream>>>(enc_ab, BencA, 24 * Dc, flag);
  k_cvt<<<32, 256, 0, stream>>>(enc_b1, BencW1, 6 * FFc, flag);
  k_cvt<<<32, 256, 0, stream>>>(enc_b2, BencW2, 6 * Dc, flag);
  k_cvt<<<32, 256, 0, stream>>>(dec_ab, BdecA, 48 * Dc, flag);
  k_cvt<<<32, 256, 0, stream>>>(dec_b1, BdecW1, 6 * FFc, flag);
  k_cvt<<<32, 256, 0, stream>>>(dec_b2, BdecW2, 6 * Dc, flag);

  // ---- helpers (R12 routing: best measured) ----
  auto qkv = [&](const u16* A, int M, const u16* Wt, long long wOff,
                 const float* bias, long long bOff, int Lseq) {
    G2 p{}; p.A = A; p.lda = Dc; p.W = Wt + wOff; p.ldw = Dc;
    p.bias = bias; p.bOff = bOff;
    p.C = qbf; p.Ck = kbf; p.Cv = vT; p.vSeg = 2;
    p.Hdim = 1; p.scale = 1.f; p.Lseq = Lseq;
    run_gemm<128, 128, 4>(p, M, 3 * Dc, Dc, 1, stream);
  };
  auto kv = [&](const u16* A, int M, const u16* Wt, long long wOff,
                const float* bias, long long bOff, int Lseq) {
    G2 p{}; p.A = A; p.lda = Dc; p.W = Wt + wOff; p.ldw = Dc;
    p.bias = bias; p.bOff = bOff;
    p.C = kbf; p.Ck = vT; p.vSeg = 1;
    p.Hdim = 1; p.scale = 1.f; p.Lseq = Lseq;
    run_gemm<128, 128, 4>(p, M, 2 * Dc, Dc, 1, stream);
  };
  auto p768 = [&](const u16* A, int M, const u16* Wt, long long wOff,
                  const float* bias, long long bOff, u16* C, int K, int relu) {
    G2 p{}; p.A = A; p.lda = K; p.W = Wt + wOff; p.ldw = K;
    p.bias = bias; p.bOff = bOff; p.C = C; p.ldc = Dc;
    p.Hdim = 1; p.scale = 1.f; p.relu = relu;
    run_gemm<128, 64, 0>(p, M, Dc, K, 1, stream);
  };
  auto ffn1 = [&](const u16* A, int M, const u16* Wt, long long wOff,
                  const float* bias, long long bOff) {
    G2 p{}; p.A = A; p.lda = Dc; p.W = Wt + wOff; p.ldw = Dc;
    p.bias = bias; p.bOff = bOff; p.C = ffmid; p.ldc = FFc;
    p.Hdim = 1; p.scale = 1.f; p.relu = 1;
    run_gemm<128, 128, 0>(p, M, FFc, Dc, 1, stream);
  };
  auto g_rel = [&]() {
    G2 p{}; p.A = simb; p.lda = LXc; p.sAb = (long long)LXc * LXc;
    p.W = aoT; p.ldw = LXc; p.sWb = (long long)Dc * LXc;
    p.C = ao2; p.ldc = Dc; p.sCb = (long long)LXc * Dc;
    p.Hdim = 1; p.scale = 1.f;
    run_gemm<128, 128, 0>(p, LXc, Dc, LXc, NB, stream);
  };

  // ---- encoder (M = 4096) ----
  for (int i = 0; i < 6; ++i) {
    int M = NB * LYc;
    long long wo = (long long)i * 4 * DD, bo = (long long)i * 4 * Dc;
    qkv(curb_y, M, WencA, wo, BencA, bo, LYc);
    k_attn<0><<<dim3(LYc / 64, NH, NB), 256, 0, stream>>>(qbf, kbf, vT, ao2, LYc, LYc);
    p768(ao2, M, WencA, wo + 3 * DD, BencA, bo + 3 * Dc, deltab, Dc, 0);
    k_lnres3<0><<<M, 256, 0, stream>>>(curb_y, deltab, enc_lg, (long long)(i*2+0)*Dc, enc_lb, (long long)(i*2+0)*Dc, flag, nullptr, 0);
    ffn1(curb_y, M, WencW1, (long long)i * DF, BencW1, (long long)i * FFc);
    p768(ffmid, M, WencW2, (long long)i * DF, BencW2, (long long)i * Dc, deltab, FFc, 0);
    if (i < 5)
      k_lnres3<0><<<M, 256, 0, stream>>>(curb_y, deltab, enc_lg, (long long)(i*2+1)*Dc, enc_lb, (long long)(i*2+1)*Dc, flag, nullptr, 0);
    else  // final encoder LN: also emit y section of d_out
      k_lnres3<1><<<M, 256, 0, stream>>>(curb_y, deltab, enc_lg, (long long)(i*2+1)*Dc, enc_lb, (long long)(i*2+1)*Dc, flag, d_out, 0);
  }

  // ---- decoder (M = 8192) ----
  for (int i = 0; i < 6; ++i) {
    int M = NB * LXc;
    for (int a = 0; a < 2; ++a) {
      long long wo = (long long)(i * 2 + a) * 4 * DD;
      long long bo = (long long)(i * 2 + a) * 4 * Dc;
      int Lk;
      if (a == 0) {
        qkv(curb_x, M, WdecA, wo, BdecA, bo, LXc);
        Lk = LXc;
      } else {
        p768(curb_x, M, WdecA, wo, BdecA, bo, qbf, Dc, 0);
        kv(curb_y, NB * LYc, WdecA, wo + DD, BdecA, bo + Dc, LYc);
        Lk = LYc;
      }
      k_attn<1><<<dim3(LXc / 64, NH, NB), 256, 0, stream>>>(qbf, kbf, vT, aoT, LXc, Lk);
      g_rel();
      p768(ao2, M, WdecA, wo + 3 * DD, BdecA, bo + 3 * Dc, deltab, Dc, 0);
      k_lnres3<0><<<M, 256, 0, stream>>>(curb_x, deltab, dec_lg, (long long)(i*3+a)*Dc, dec_lb, (long long)(i*3+a)*Dc, flag, nullptr, 0);
    }
    ffn1(curb_x, M, WdecW1, (long long)i * DF, BdecW1, (long long)i * FFc);
    p768(ffmid, M, WdecW2, (long long)i * DF, BdecW2, (long long)i * Dc, deltab, FFc, 0);
    if (i < 5)
      k_lnres3<0><<<M, 256, 0, stream>>>(curb_x, deltab, dec_lg, (long long)(i*3+2)*Dc, dec_lb, (long long)(i*3+2)*Dc, flag, nullptr, 0);
    else  // final decoder LN: also emit x section of d_out
      k_lnres3<1><<<M, 256, 0, stream>>>(curb_x, deltab, dec_lg, (long long)(i*3+2)*Dc, dec_lb, (long long)(i*3+2)*Dc, flag, d_out, NYt);
  }
}